// Round 5
// baseline (386.512 us; speedup 1.0000x reference)
//
#include <hip/hip_runtime.h>
#include <hip/hip_bf16.h>

typedef __bf16 bf16;
typedef bf16 bf16x8 __attribute__((ext_vector_type(8)));
typedef float f32x4 __attribute__((ext_vector_type(4)));

#define MFMA16(a, b, c) __builtin_amdgcn_mfma_f32_16x16x32_bf16((a), (b), (c), 0, 0, 0)

// Problem constants
static constexpr int TT    = 2048;
static constexpr int CC    = 768;
static constexpr int NHEAD = 12;
static constexpr int DHEAD = 64;

__device__ inline bf16x8 cvt8(const float4& a, const float4& b) {
    bf16x8 o;
    o[0] = (bf16)a.x; o[1] = (bf16)a.y; o[2] = (bf16)a.z; o[3] = (bf16)a.w;
    o[4] = (bf16)b.x; o[5] = (bf16)b.y; o[6] = (bf16)b.z; o[7] = (bf16)b.w;
    return o;
}

struct BPtrs { const float* p[5]; };

// ---------------------------------------------------------------------------
// RoPE cos/sin tables: [2048][32] each, fp32
// ---------------------------------------------------------------------------
__global__ __launch_bounds__(256) void rope_table(float* __restrict__ cosT, float* __restrict__ sinT) {
    int i = blockIdx.x * 256 + threadIdx.x;   // 65536
    int t = i >> 5, j = i & 31;
    float inv = 1.0f / powf(10000.0f, (float)(2 * j) / 64.0f);
    float f = (float)t * inv;
    cosT[i] = cosf(f);
    sinT[i] = sinf(f);
}

// ---------------------------------------------------------------------------
// RMSNorm row kernel: 768 floats per row, 256 threads/block
// ---------------------------------------------------------------------------
__global__ __launch_bounds__(256) void rmsnorm(const float* __restrict__ x, bf16* __restrict__ out) {
    int row = blockIdx.x;
    const float* xr = x + (long)row * CC;
    int tid = threadIdx.x;
    float v0 = xr[tid], v1 = xr[tid + 256], v2 = xr[tid + 512];
    float ss = v0 * v0 + v1 * v1 + v2 * v2;
    #pragma unroll
    for (int off = 32; off > 0; off >>= 1) ss += __shfl_down(ss, off);
    __shared__ float red[4];
    if ((tid & 63) == 0) red[tid >> 6] = ss;
    __syncthreads();
    float tot = red[0] + red[1] + red[2] + red[3];
    float sc = rsqrtf(tot * (1.0f / 768.0f) + 1e-6f);
    bf16* o = out + (long)row * CC;
    o[tid]       = (bf16)(v0 * sc);
    o[tid + 256] = (bf16)(v1 * sc);
    o[tid + 512] = (bf16)(v2 * sc);
}

// ---------------------------------------------------------------------------
// GEMM: C[M,N] = A[M,K] @ B[N,K]^T.  A bf16; B fp32 (converted during staging).
// B may be split into vertical parts of partRows rows each (BPtrs).
// EPI 0: outb = bf16(acc)
// EPI 1: outf = res + acc              (fp32 out)
// EPI 2: outf = res + bias + acc       (fp32 out -- d_out is float*!)
// 128x128 tile, BK=32, 4 waves (2x2), 4x4 16x16 fragments per wave.
// ---------------------------------------------------------------------------
template <int EPI>
__global__ __launch_bounds__(256) void gemm_bt(
    const bf16* __restrict__ A, BPtrs Bp, int partRows,
    bf16* __restrict__ outb, float* __restrict__ outf,
    const float* __restrict__ res, const float* __restrict__ bias,
    int M, int N, int K)
{
    constexpr int LDR = 40;  // LDS row stride (pad 32->40)
    __shared__ bf16 Al[128 * LDR];
    __shared__ bf16 Bl[128 * LDR];

    const int tid  = threadIdx.x;
    const int lane = tid & 63;
    const int wave = tid >> 6;
    const int wr = wave >> 1, wc = wave & 1;
    const int l15 = lane & 15, lhi = lane >> 4;
    const int bm = blockIdx.x * 128, bn = blockIdx.y * 128;

    const int seg = bn / partRows;                       // tile fully inside one part (768 % 128 == 0)
    const float* Bbase = Bp.p[seg] + (long)(bn - seg * partRows) * K;

    // staging: each thread covers (srow, scol) and (srow+64, scol), 8 elems each
    const int srow = tid >> 2;          // 0..63
    const int scol = (tid & 3) * 8;     // 0,8,16,24

    const bf16*  Ag = A + (long)(bm + srow) * K + scol;
    const float* Bg = Bbase + (long)srow * K + scol;

    f32x4 acc[4][4] = {};

    const int nk = K / 32;
    bf16x8 ga0 = *(const bf16x8*)(Ag);
    bf16x8 ga1 = *(const bf16x8*)(Ag + (long)64 * K);
    float4 gb0a = *(const float4*)(Bg);
    float4 gb0b = *(const float4*)(Bg + 4);
    float4 gb1a = *(const float4*)(Bg + (long)64 * K);
    float4 gb1b = *(const float4*)(Bg + (long)64 * K + 4);

    for (int t = 0; t < nk; ++t) {
        __syncthreads();
        *(bf16x8*)(&Al[srow * LDR + scol])        = ga0;
        *(bf16x8*)(&Al[(srow + 64) * LDR + scol]) = ga1;
        *(bf16x8*)(&Bl[srow * LDR + scol])        = cvt8(gb0a, gb0b);
        *(bf16x8*)(&Bl[(srow + 64) * LDR + scol]) = cvt8(gb1a, gb1b);
        __syncthreads();
        if (t + 1 < nk) {
            const bf16*  An = Ag + (t + 1) * 32;
            const float* Bn = Bg + (t + 1) * 32;
            ga0 = *(const bf16x8*)(An);
            ga1 = *(const bf16x8*)(An + (long)64 * K);
            gb0a = *(const float4*)(Bn);
            gb0b = *(const float4*)(Bn + 4);
            gb1a = *(const float4*)(Bn + (long)64 * K);
            gb1b = *(const float4*)(Bn + (long)64 * K + 4);
        }
        bf16x8 a[4], b[4];
        #pragma unroll
        for (int m = 0; m < 4; ++m)
            a[m] = *(const bf16x8*)(&Al[(wr * 64 + m * 16 + l15) * LDR + lhi * 8]);
        #pragma unroll
        for (int n = 0; n < 4; ++n)
            b[n] = *(const bf16x8*)(&Bl[(wc * 64 + n * 16 + l15) * LDR + lhi * 8]);
        #pragma unroll
        for (int m = 0; m < 4; ++m)
            #pragma unroll
            for (int n = 0; n < 4; ++n)
                acc[m][n] = MFMA16(a[m], b[n], acc[m][n]);
    }

    // epilogue: lane holds C[row0+r][col]
    #pragma unroll
    for (int m = 0; m < 4; ++m) {
        #pragma unroll
        for (int n = 0; n < 4; ++n) {
            int row0 = bm + wr * 64 + m * 16 + lhi * 4;
            int col  = bn + wc * 64 + n * 16 + l15;
            #pragma unroll
            for (int r = 0; r < 4; ++r) {
                long idx = (long)(row0 + r) * N + col;
                float v = acc[m][n][r];
                if (EPI == 0) {
                    outb[idx] = (bf16)v;
                } else if (EPI == 1) {
                    outf[idx] = res[idx] + v;
                } else {
                    outf[idx] = res[idx] + bias[col] + v;   // fp32 final output
                }
            }
        }
    }
}

// ---------------------------------------------------------------------------
// Fused MLP-up: hid = (A@B1^T) * (A@B2^T), elementwise product of two GEMMs.
// A bf16 [M,K]; B1,B2 fp32 [N,K]. out bf16 [M,N].
// ---------------------------------------------------------------------------
__global__ __launch_bounds__(256) void gemm_mlp_up(
    const bf16* __restrict__ A, const float* __restrict__ B1, const float* __restrict__ B2,
    bf16* __restrict__ out, int M, int N, int K)
{
    constexpr int LDR = 40;
    __shared__ bf16 Al[128 * LDR];
    __shared__ bf16 B1l[128 * LDR];
    __shared__ bf16 B2l[128 * LDR];

    const int tid  = threadIdx.x;
    const int lane = tid & 63;
    const int wave = tid >> 6;
    const int wr = wave >> 1, wc = wave & 1;
    const int l15 = lane & 15, lhi = lane >> 4;
    const int bm = blockIdx.x * 128, bn = blockIdx.y * 128;

    const int srow = tid >> 2;
    const int scol = (tid & 3) * 8;

    const bf16*  Ag  = A  + (long)(bm + srow) * K + scol;
    const float* B1g = B1 + (long)(bn + srow) * K + scol;
    const float* B2g = B2 + (long)(bn + srow) * K + scol;

    f32x4 acc1[4][4] = {};
    f32x4 acc2[4][4] = {};

    const int nk = K / 32;
    bf16x8 ga0 = *(const bf16x8*)(Ag);
    bf16x8 ga1 = *(const bf16x8*)(Ag + (long)64 * K);
    float4 g1a0 = *(const float4*)(B1g),               g1b0 = *(const float4*)(B1g + 4);
    float4 g1a1 = *(const float4*)(B1g + (long)64 * K), g1b1 = *(const float4*)(B1g + (long)64 * K + 4);
    float4 g2a0 = *(const float4*)(B2g),               g2b0 = *(const float4*)(B2g + 4);
    float4 g2a1 = *(const float4*)(B2g + (long)64 * K), g2b1 = *(const float4*)(B2g + (long)64 * K + 4);

    for (int t = 0; t < nk; ++t) {
        __syncthreads();
        *(bf16x8*)(&Al[srow * LDR + scol])         = ga0;
        *(bf16x8*)(&Al[(srow + 64) * LDR + scol])  = ga1;
        *(bf16x8*)(&B1l[srow * LDR + scol])        = cvt8(g1a0, g1b0);
        *(bf16x8*)(&B1l[(srow + 64) * LDR + scol]) = cvt8(g1a1, g1b1);
        *(bf16x8*)(&B2l[srow * LDR + scol])        = cvt8(g2a0, g2b0);
        *(bf16x8*)(&B2l[(srow + 64) * LDR + scol]) = cvt8(g2a1, g2b1);
        __syncthreads();
        if (t + 1 < nk) {
            const bf16*  An  = Ag  + (t + 1) * 32;
            const float* B1n = B1g + (t + 1) * 32;
            const float* B2n = B2g + (t + 1) * 32;
            ga0 = *(const bf16x8*)(An);
            ga1 = *(const bf16x8*)(An + (long)64 * K);
            g1a0 = *(const float4*)(B1n);                g1b0 = *(const float4*)(B1n + 4);
            g1a1 = *(const float4*)(B1n + (long)64 * K); g1b1 = *(const float4*)(B1n + (long)64 * K + 4);
            g2a0 = *(const float4*)(B2n);                g2b0 = *(const float4*)(B2n + 4);
            g2a1 = *(const float4*)(B2n + (long)64 * K); g2b1 = *(const float4*)(B2n + (long)64 * K + 4);
        }
        bf16x8 a[4], b1[4], b2[4];
        #pragma unroll
        for (int m = 0; m < 4; ++m)
            a[m] = *(const bf16x8*)(&Al[(wr * 64 + m * 16 + l15) * LDR + lhi * 8]);
        #pragma unroll
        for (int n = 0; n < 4; ++n) {
            b1[n] = *(const bf16x8*)(&B1l[(wc * 64 + n * 16 + l15) * LDR + lhi * 8]);
            b2[n] = *(const bf16x8*)(&B2l[(wc * 64 + n * 16 + l15) * LDR + lhi * 8]);
        }
        #pragma unroll
        for (int m = 0; m < 4; ++m)
            #pragma unroll
            for (int n = 0; n < 4; ++n) {
                acc1[m][n] = MFMA16(a[m], b1[n], acc1[m][n]);
                acc2[m][n] = MFMA16(a[m], b2[n], acc2[m][n]);
            }
    }

    #pragma unroll
    for (int m = 0; m < 4; ++m) {
        #pragma unroll
        for (int n = 0; n < 4; ++n) {
            int row0 = bm + wr * 64 + m * 16 + lhi * 4;
            int col  = bn + wc * 64 + n * 16 + l15;
            #pragma unroll
            for (int r = 0; r < 4; ++r) {
                out[(long)(row0 + r) * N + col] = (bf16)(acc1[m][n][r] * acc2[m][n][r]);
            }
        }
    }
}

// ---------------------------------------------------------------------------
// In-place RoPE on q,k,q2,k2 (cols 0..3071 of qkv[t][3840])
// ---------------------------------------------------------------------------
__global__ __launch_bounds__(256) void rope_apply(bf16* __restrict__ qkv,
                                                  const float* __restrict__ cosT,
                                                  const float* __restrict__ sinT) {
    int t = blockIdx.x;
    for (int it = threadIdx.x; it < 4 * NHEAD * 32; it += 256) {
        int mat = it / (NHEAD * 32);
        int rem = it % (NHEAD * 32);
        int hh = rem / 32, j = rem % 32;
        long base = (long)t * 3840 + mat * CC + hh * DHEAD + j;
        float c = cosT[t * 32 + j], s = sinT[t * 32 + j];
        float x1 = (float)qkv[base], x2 = (float)qkv[base + 32];
        qkv[base]      = (bf16)(x1 * c + x2 * s);
        qkv[base + 32] = (bf16)(-x1 * s + x2 * c);
    }
}

// ---------------------------------------------------------------------------
// Fused causal quadratic-gated attention:
//   z[q,h,:] = sum_{k<=q} (S1[q,k]*S2[q,k]/4096) * v[k,h,:]
// ---------------------------------------------------------------------------
__global__ __launch_bounds__(256) void attn(const bf16* __restrict__ qkv, bf16* __restrict__ z) {
    constexpr int LDK = 72;
    __shared__ bf16 Kl[64 * LDK];
    __shared__ bf16 K2l[64 * LDK];
    __shared__ bf16 Vt[64 * LDK];       // Vt[d][k]
    __shared__ bf16 Pl[4][16 * LDK];    // per-wave P tile [16 q][64 k]

    const int tid = threadIdx.x, lane = tid & 63, wave = tid >> 6;
    const int l15 = lane & 15, lhi = lane >> 4;
    const int h = blockIdx.y, qt = blockIdx.x;
    const int q0w = qt * 64 + wave * 16;

    const bf16* qbase = qkv + (long)(q0w + l15) * 3840 + h * DHEAD + lhi * 8;
    const bf16x8 qa0  = *(const bf16x8*)(qbase);
    const bf16x8 qa1  = *(const bf16x8*)(qbase + 32);
    const bf16x8 q2a0 = *(const bf16x8*)(qbase + 1536);
    const bf16x8 q2a1 = *(const bf16x8*)(qbase + 1536 + 32);

    f32x4 zacc[4] = {};

    const int trow = tid >> 3;        // 0..31
    const int tcol = (tid & 7) * 8;   // 0..56

    for (int kt = 0; kt <= qt; ++kt) {
        __syncthreads();
        #pragma unroll
        for (int r2 = 0; r2 < 2; ++r2) {
            int krow = r2 * 32 + trow;
            const bf16* src = qkv + (long)(kt * 64 + krow) * 3840 + h * DHEAD + tcol;
            bf16x8 kv  = *(const bf16x8*)(src + 768);
            bf16x8 k2v = *(const bf16x8*)(src + 2304);
            bf16x8 vv  = *(const bf16x8*)(src + 3072);
            *(bf16x8*)(&Kl[krow * LDK + tcol])  = kv;
            *(bf16x8*)(&K2l[krow * LDK + tcol]) = k2v;
            #pragma unroll
            for (int e = 0; e < 8; ++e) Vt[(tcol + e) * LDK + krow] = vv[e];
        }
        __syncthreads();

        f32x4 s1[4] = {}, s2[4] = {};
        #pragma unroll
        for (int nf = 0; nf < 4; ++nf) {
            bf16x8 kb0 = *(const bf16x8*)(&Kl[(nf * 16 + l15) * LDK + lhi * 8]);
            s1[nf] = MFMA16(qa0, kb0, s1[nf]);
            bf16x8 kb1 = *(const bf16x8*)(&Kl[(nf * 16 + l15) * LDK + 32 + lhi * 8]);
            s1[nf] = MFMA16(qa1, kb1, s1[nf]);
            bf16x8 k2b0 = *(const bf16x8*)(&K2l[(nf * 16 + l15) * LDK + lhi * 8]);
            s2[nf] = MFMA16(q2a0, k2b0, s2[nf]);
            bf16x8 k2b1 = *(const bf16x8*)(&K2l[(nf * 16 + l15) * LDK + 32 + lhi * 8]);
            s2[nf] = MFMA16(q2a1, k2b1, s2[nf]);
        }

        #pragma unroll
        for (int nf = 0; nf < 4; ++nf) {
            #pragma unroll
            for (int r = 0; r < 4; ++r) {
                int qg = q0w + lhi * 4 + r;
                int kg = kt * 64 + nf * 16 + l15;
                float p = (kg <= qg) ? s1[nf][r] * s2[nf][r] * (1.0f / 4096.0f) : 0.0f;
                Pl[wave][(lhi * 4 + r) * LDK + nf * 16 + l15] = (bf16)p;
            }
        }

        #pragma unroll
        for (int kk = 0; kk < 2; ++kk) {
            bf16x8 pa = *(const bf16x8*)(&Pl[wave][l15 * LDK + kk * 32 + lhi * 8]);
            #pragma unroll
            for (int f = 0; f < 4; ++f) {
                bf16x8 vb = *(const bf16x8*)(&Vt[(f * 16 + l15) * LDK + kk * 32 + lhi * 8]);
                zacc[f] = MFMA16(pa, vb, zacc[f]);
            }
        }
    }

    #pragma unroll
    for (int f = 0; f < 4; ++f) {
        #pragma unroll
        for (int r = 0; r < 4; ++r) {
            z[(long)(q0w + lhi * 4 + r) * CC + h * DHEAD + f * 16 + l15] = (bf16)zacc[f][r];
        }
    }
}

// ---------------------------------------------------------------------------
extern "C" void kernel_launch(void* const* d_in, const int* in_sizes, int n_in,
                              void* d_out, int out_size, void* d_ws, size_t ws_size,
                              hipStream_t stream) {
    const float* x   = (const float*)d_in[0];
    const float* Wq  = (const float*)d_in[1];
    const float* Wk  = (const float*)d_in[2];
    const float* Wq2 = (const float*)d_in[3];
    const float* Wk2 = (const float*)d_in[4];
    const float* Wv  = (const float*)d_in[5];
    const float* Wo  = (const float*)d_in[6];
    const float* Wp1 = (const float*)d_in[7];
    const float* Wp2 = (const float*)d_in[8];
    const float* Wd  = (const float*)d_in[9];
    const float* bd  = (const float*)d_in[10];

    char* ws = (char*)d_ws;
    size_t off = 0;
    auto alloc = [&](size_t bytes) {
        void* p = ws + off;
        off += (bytes + 255) & ~(size_t)255;
        return p;
    };
    // Total = 44.4 MB.
    float* xmid  = (float*)alloc(2048l * 768 * 4);
    bf16*  h2    = (bf16*)alloc(2048l * 768 * 2);
    bf16*  hid   = (bf16*)alloc(2048l * 3072 * 2);
    bf16*  h1    = (bf16*)alloc(2048l * 768 * 2);
    float* cosT  = (float*)alloc(2048l * 32 * 4);
    float* sinT  = (float*)alloc(2048l * 32 * 4);
    bf16*  zbuf  = (bf16*)alloc(2048l * 768 * 2);
    bf16*  qkv   = (bf16*)alloc(2048l * 3840 * 2);

    BPtrs BQKV = {{Wq, Wk, Wq2, Wk2, Wv}};
    BPtrs BWO  = {{Wo, Wo, Wo, Wo, Wo}};
    BPtrs BWD  = {{Wd, Wd, Wd, Wd, Wd}};

    rope_table<<<dim3(256), 256, 0, stream>>>(cosT, sinT);
    rmsnorm<<<dim3(2048), 256, 0, stream>>>(x, h1);
    gemm_bt<0><<<dim3(16, 30), 256, 0, stream>>>(h1, BQKV, 768, qkv, nullptr, nullptr, nullptr, 2048, 3840, 768);
    rope_apply<<<dim3(2048), 256, 0, stream>>>(qkv, cosT, sinT);
    attn<<<dim3(32, 12), 256, 0, stream>>>(qkv, zbuf);
    gemm_bt<1><<<dim3(16, 6), 256, 0, stream>>>(zbuf, BWO, 768, nullptr, xmid, x, nullptr, 2048, 768, 768);
    rmsnorm<<<dim3(2048), 256, 0, stream>>>(xmid, h2);
    gemm_mlp_up<<<dim3(16, 24), 256, 0, stream>>>(h2, Wp1, Wp2, hid, 2048, 3072, 768);
    gemm_bt<2><<<dim3(16, 6), 256, 0, stream>>>(hid, BWD, 768, nullptr, (float*)d_out, xmid, bd, 2048, 768, 3072);
}

// Round 6
// 352.413 us; speedup vs baseline: 1.0968x; 1.0968x over previous
//
#include <hip/hip_runtime.h>
#include <hip/hip_bf16.h>

typedef __bf16 bf16;
typedef bf16 bf16x8 __attribute__((ext_vector_type(8)));
typedef float f32x4 __attribute__((ext_vector_type(4)));

#define MFMA16(a, b, c) __builtin_amdgcn_mfma_f32_16x16x32_bf16((a), (b), (c), 0, 0, 0)

// Problem constants
static constexpr int TT    = 2048;
static constexpr int CC    = 768;
static constexpr int NHEAD = 12;
static constexpr int DHEAD = 64;

__device__ inline bf16x8 cvt8(const float4& a, const float4& b) {
    bf16x8 o;
    o[0] = (bf16)a.x; o[1] = (bf16)a.y; o[2] = (bf16)a.z; o[3] = (bf16)a.w;
    o[4] = (bf16)b.x; o[5] = (bf16)b.y; o[6] = (bf16)b.z; o[7] = (bf16)b.w;
    return o;
}

struct BPtrs { const float* p[5]; };

// ---------------------------------------------------------------------------
__global__ __launch_bounds__(256) void zero_f32(float* __restrict__ p) {
    int i = (blockIdx.x * 256 + threadIdx.x) * 4;
    *(f32x4*)(p + i) = f32x4{0.f, 0.f, 0.f, 0.f};
}

// ---------------------------------------------------------------------------
// RoPE cos/sin tables: [2048][32] each, fp32
// ---------------------------------------------------------------------------
__global__ __launch_bounds__(256) void rope_table(float* __restrict__ cosT, float* __restrict__ sinT) {
    int i = blockIdx.x * 256 + threadIdx.x;   // 65536
    int t = i >> 5, j = i & 31;
    float inv = 1.0f / powf(10000.0f, (float)(2 * j) / 64.0f);
    float f = (float)t * inv;
    cosT[i] = cosf(f);
    sinT[i] = sinf(f);
}

// ---------------------------------------------------------------------------
// RMSNorm row kernel: 768 floats per row, 256 threads/block
// ---------------------------------------------------------------------------
__global__ __launch_bounds__(256) void rmsnorm(const float* __restrict__ x, bf16* __restrict__ out) {
    int row = blockIdx.x;
    const float* xr = x + (long)row * CC;
    int tid = threadIdx.x;
    float v0 = xr[tid], v1 = xr[tid + 256], v2 = xr[tid + 512];
    float ss = v0 * v0 + v1 * v1 + v2 * v2;
    #pragma unroll
    for (int off = 32; off > 0; off >>= 1) ss += __shfl_down(ss, off);
    __shared__ float red[4];
    if ((tid & 63) == 0) red[tid >> 6] = ss;
    __syncthreads();
    float tot = red[0] + red[1] + red[2] + red[3];
    float sc = rsqrtf(tot * (1.0f / 768.0f) + 1e-6f);
    bf16* o = out + (long)row * CC;
    o[tid]       = (bf16)(v0 * sc);
    o[tid + 256] = (bf16)(v1 * sc);
    o[tid + 512] = (bf16)(v2 * sc);
}

// ---------------------------------------------------------------------------
// GEMM: C[M,N] = A[M,K] @ B[N,K]^T.  A bf16 (or fp32 if AF32); B fp32
// (converted during staging). B split into vertical parts (BPtrs).
// EPI 0: outb = bf16(acc)
// EPI 1: outf = res + acc              (fp32 out)
// EPI 2: outf = res + bias + acc       (fp32 out -- d_out is float*)
// 128x128 tile, BK=32, 4 waves (2x2), 4x4 16x16 fragments per wave.
// ---------------------------------------------------------------------------
template <int EPI, bool AF32>
__global__ __launch_bounds__(256) void gemm_bt(
    const void* __restrict__ Av, BPtrs Bp, int partRows,
    bf16* __restrict__ outb, float* __restrict__ outf,
    const float* __restrict__ res, const float* __restrict__ bias,
    int M, int N, int K)
{
    constexpr int LDR = 40;  // LDS row stride (pad 32->40)
    __shared__ bf16 Al[128 * LDR];
    __shared__ bf16 Bl[128 * LDR];

    const int tid  = threadIdx.x;
    const int lane = tid & 63;
    const int wave = tid >> 6;
    const int wr = wave >> 1, wc = wave & 1;
    const int l15 = lane & 15, lhi = lane >> 4;
    const int bm = blockIdx.x * 128, bn = blockIdx.y * 128;

    const int seg = bn / partRows;
    const float* Bbase = Bp.p[seg] + (long)(bn - seg * partRows) * K;

    const int srow = tid >> 2;          // 0..63
    const int scol = (tid & 3) * 8;     // 0,8,16,24

    const bf16*  Ag  = (const bf16*)Av  + (long)(bm + srow) * K + scol;
    const float* Agf = (const float*)Av + (long)(bm + srow) * K + scol;
    const float* Bg  = Bbase + (long)srow * K + scol;

    f32x4 acc[4][4] = {};

    const int nk = K / 32;
    bf16x8 ga0, ga1;
    float4 fa0a, fa0b, fa1a, fa1b;
    if constexpr (AF32) {
        fa0a = *(const float4*)(Agf);
        fa0b = *(const float4*)(Agf + 4);
        fa1a = *(const float4*)(Agf + (long)64 * K);
        fa1b = *(const float4*)(Agf + (long)64 * K + 4);
    } else {
        ga0 = *(const bf16x8*)(Ag);
        ga1 = *(const bf16x8*)(Ag + (long)64 * K);
    }
    float4 gb0a = *(const float4*)(Bg);
    float4 gb0b = *(const float4*)(Bg + 4);
    float4 gb1a = *(const float4*)(Bg + (long)64 * K);
    float4 gb1b = *(const float4*)(Bg + (long)64 * K + 4);

    for (int t = 0; t < nk; ++t) {
        __syncthreads();
        if constexpr (AF32) {
            *(bf16x8*)(&Al[srow * LDR + scol])        = cvt8(fa0a, fa0b);
            *(bf16x8*)(&Al[(srow + 64) * LDR + scol]) = cvt8(fa1a, fa1b);
        } else {
            *(bf16x8*)(&Al[srow * LDR + scol])        = ga0;
            *(bf16x8*)(&Al[(srow + 64) * LDR + scol]) = ga1;
        }
        *(bf16x8*)(&Bl[srow * LDR + scol])        = cvt8(gb0a, gb0b);
        *(bf16x8*)(&Bl[(srow + 64) * LDR + scol]) = cvt8(gb1a, gb1b);
        __syncthreads();
        if (t + 1 < nk) {
            if constexpr (AF32) {
                const float* An = Agf + (t + 1) * 32;
                fa0a = *(const float4*)(An);
                fa0b = *(const float4*)(An + 4);
                fa1a = *(const float4*)(An + (long)64 * K);
                fa1b = *(const float4*)(An + (long)64 * K + 4);
            } else {
                const bf16* An = Ag + (t + 1) * 32;
                ga0 = *(const bf16x8*)(An);
                ga1 = *(const bf16x8*)(An + (long)64 * K);
            }
            const float* Bn = Bg + (t + 1) * 32;
            gb0a = *(const float4*)(Bn);
            gb0b = *(const float4*)(Bn + 4);
            gb1a = *(const float4*)(Bn + (long)64 * K);
            gb1b = *(const float4*)(Bn + (long)64 * K + 4);
        }
        bf16x8 a[4], b[4];
        #pragma unroll
        for (int m = 0; m < 4; ++m)
            a[m] = *(const bf16x8*)(&Al[(wr * 64 + m * 16 + l15) * LDR + lhi * 8]);
        #pragma unroll
        for (int n = 0; n < 4; ++n)
            b[n] = *(const bf16x8*)(&Bl[(wc * 64 + n * 16 + l15) * LDR + lhi * 8]);
        #pragma unroll
        for (int m = 0; m < 4; ++m)
            #pragma unroll
            for (int n = 0; n < 4; ++n)
                acc[m][n] = MFMA16(a[m], b[n], acc[m][n]);
    }

    #pragma unroll
    for (int m = 0; m < 4; ++m) {
        #pragma unroll
        for (int n = 0; n < 4; ++n) {
            int row0 = bm + wr * 64 + m * 16 + lhi * 4;
            int col  = bn + wc * 64 + n * 16 + l15;
            #pragma unroll
            for (int r = 0; r < 4; ++r) {
                long idx = (long)(row0 + r) * N + col;
                float v = acc[m][n][r];
                if (EPI == 0) {
                    outb[idx] = (bf16)v;
                } else if (EPI == 1) {
                    outf[idx] = res[idx] + v;
                } else {
                    outf[idx] = res[idx] + bias[col] + v;   // fp32 final output
                }
            }
        }
    }
}

// ---------------------------------------------------------------------------
// Fused MLP-up: hid = (A@B1^T) * (A@B2^T)
// ---------------------------------------------------------------------------
__global__ __launch_bounds__(256) void gemm_mlp_up(
    const bf16* __restrict__ A, const float* __restrict__ B1, const float* __restrict__ B2,
    bf16* __restrict__ out, int M, int N, int K)
{
    constexpr int LDR = 40;
    __shared__ bf16 Al[128 * LDR];
    __shared__ bf16 B1l[128 * LDR];
    __shared__ bf16 B2l[128 * LDR];

    const int tid  = threadIdx.x;
    const int lane = tid & 63;
    const int wave = tid >> 6;
    const int wr = wave >> 1, wc = wave & 1;
    const int l15 = lane & 15, lhi = lane >> 4;
    const int bm = blockIdx.x * 128, bn = blockIdx.y * 128;

    const int srow = tid >> 2;
    const int scol = (tid & 3) * 8;

    const bf16*  Ag  = A  + (long)(bm + srow) * K + scol;
    const float* B1g = B1 + (long)(bn + srow) * K + scol;
    const float* B2g = B2 + (long)(bn + srow) * K + scol;

    f32x4 acc1[4][4] = {};
    f32x4 acc2[4][4] = {};

    const int nk = K / 32;
    bf16x8 ga0 = *(const bf16x8*)(Ag);
    bf16x8 ga1 = *(const bf16x8*)(Ag + (long)64 * K);
    float4 g1a0 = *(const float4*)(B1g),               g1b0 = *(const float4*)(B1g + 4);
    float4 g1a1 = *(const float4*)(B1g + (long)64 * K), g1b1 = *(const float4*)(B1g + (long)64 * K + 4);
    float4 g2a0 = *(const float4*)(B2g),               g2b0 = *(const float4*)(B2g + 4);
    float4 g2a1 = *(const float4*)(B2g + (long)64 * K), g2b1 = *(const float4*)(B2g + (long)64 * K + 4);

    for (int t = 0; t < nk; ++t) {
        __syncthreads();
        *(bf16x8*)(&Al[srow * LDR + scol])         = ga0;
        *(bf16x8*)(&Al[(srow + 64) * LDR + scol])  = ga1;
        *(bf16x8*)(&B1l[srow * LDR + scol])        = cvt8(g1a0, g1b0);
        *(bf16x8*)(&B1l[(srow + 64) * LDR + scol]) = cvt8(g1a1, g1b1);
        *(bf16x8*)(&B2l[srow * LDR + scol])        = cvt8(g2a0, g2b0);
        *(bf16x8*)(&B2l[(srow + 64) * LDR + scol]) = cvt8(g2a1, g2b1);
        __syncthreads();
        if (t + 1 < nk) {
            const bf16*  An  = Ag  + (t + 1) * 32;
            const float* B1n = B1g + (t + 1) * 32;
            const float* B2n = B2g + (t + 1) * 32;
            ga0 = *(const bf16x8*)(An);
            ga1 = *(const bf16x8*)(An + (long)64 * K);
            g1a0 = *(const float4*)(B1n);                g1b0 = *(const float4*)(B1n + 4);
            g1a1 = *(const float4*)(B1n + (long)64 * K); g1b1 = *(const float4*)(B1n + (long)64 * K + 4);
            g2a0 = *(const float4*)(B2n);                g2b0 = *(const float4*)(B2n + 4);
            g2a1 = *(const float4*)(B2n + (long)64 * K); g2b1 = *(const float4*)(B2n + (long)64 * K + 4);
        }
        bf16x8 a[4], b1[4], b2[4];
        #pragma unroll
        for (int m = 0; m < 4; ++m)
            a[m] = *(const bf16x8*)(&Al[(wr * 64 + m * 16 + l15) * LDR + lhi * 8]);
        #pragma unroll
        for (int n = 0; n < 4; ++n) {
            b1[n] = *(const bf16x8*)(&B1l[(wc * 64 + n * 16 + l15) * LDR + lhi * 8]);
            b2[n] = *(const bf16x8*)(&B2l[(wc * 64 + n * 16 + l15) * LDR + lhi * 8]);
        }
        #pragma unroll
        for (int m = 0; m < 4; ++m)
            #pragma unroll
            for (int n = 0; n < 4; ++n) {
                acc1[m][n] = MFMA16(a[m], b1[n], acc1[m][n]);
                acc2[m][n] = MFMA16(a[m], b2[n], acc2[m][n]);
            }
    }

    #pragma unroll
    for (int m = 0; m < 4; ++m) {
        #pragma unroll
        for (int n = 0; n < 4; ++n) {
            int row0 = bm + wr * 64 + m * 16 + lhi * 4;
            int col  = bn + wc * 64 + n * 16 + l15;
            #pragma unroll
            for (int r = 0; r < 4; ++r) {
                out[(long)(row0 + r) * N + col] = (bf16)(acc1[m][n][r] * acc2[m][n][r]);
            }
        }
    }
}

// ---------------------------------------------------------------------------
// In-place RoPE on q,k,q2,k2 (cols 0..3071 of qkv[t][3840])
// ---------------------------------------------------------------------------
__global__ __launch_bounds__(256) void rope_apply(bf16* __restrict__ qkv,
                                                  const float* __restrict__ cosT,
                                                  const float* __restrict__ sinT) {
    int t = blockIdx.x;
    for (int it = threadIdx.x; it < 4 * NHEAD * 32; it += 256) {
        int mat = it / (NHEAD * 32);
        int rem = it % (NHEAD * 32);
        int hh = rem / 32, j = rem % 32;
        long base = (long)t * 3840 + mat * CC + hh * DHEAD + j;
        float c = cosT[t * 32 + j], s = sinT[t * 32 + j];
        float x1 = (float)qkv[base], x2 = (float)qkv[base + 32];
        qkv[base]      = (bf16)(x1 * c + x2 * s);
        qkv[base + 32] = (bf16)(-x1 * s + x2 * c);
    }
}

// ---------------------------------------------------------------------------
// Split-K causal quadratic-gated attention:
//   z[q,h,:] += sum_{k in chunk} (S1*S2/4096) * v[k,h,:]   (fp32 atomicAdd)
// block = (qt, h, s): s indexes one of up to 4 balanced contiguous k-chunks
// of the qt+1 valid k-tiles. 1464 valid blocks -> 4 blocks/CU resident.
// ---------------------------------------------------------------------------
__global__ __launch_bounds__(256) void attn(const bf16* __restrict__ qkv, float* __restrict__ z) {
    constexpr int LDK = 72;
    __shared__ bf16 Kl[64 * LDK];
    __shared__ bf16 K2l[64 * LDK];
    __shared__ bf16 Vt[64 * LDK];       // Vt[d][k]
    __shared__ bf16 Pl[4][16 * LDK];    // per-wave P tile [16 q][64 k]

    const int qt = blockIdx.x, h = blockIdx.y, s = blockIdx.z;
    const int nkt  = qt + 1;
    const int base = nkt >> 2, rem = nkt & 3;
    const int len  = base + (s < rem ? 1 : 0);
    if (len == 0) return;                       // uniform per block
    const int k0 = s * base + min(s, rem);

    const int tid = threadIdx.x, lane = tid & 63, wave = tid >> 6;
    const int l15 = lane & 15, lhi = lane >> 4;
    const int q0w = qt * 64 + wave * 16;

    const bf16* qbase = qkv + (long)(q0w + l15) * 3840 + h * DHEAD + lhi * 8;
    const bf16x8 qa0  = *(const bf16x8*)(qbase);
    const bf16x8 qa1  = *(const bf16x8*)(qbase + 32);
    const bf16x8 q2a0 = *(const bf16x8*)(qbase + 1536);
    const bf16x8 q2a1 = *(const bf16x8*)(qbase + 1536 + 32);

    f32x4 zacc[4] = {};

    const int trow = tid >> 3;        // 0..31
    const int tcol = (tid & 7) * 8;   // 0..56

    for (int kt = k0; kt < k0 + len; ++kt) {
        __syncthreads();
        #pragma unroll
        for (int r2 = 0; r2 < 2; ++r2) {
            int krow = r2 * 32 + trow;
            const bf16* src = qkv + (long)(kt * 64 + krow) * 3840 + h * DHEAD + tcol;
            bf16x8 kv  = *(const bf16x8*)(src + 768);
            bf16x8 k2v = *(const bf16x8*)(src + 2304);
            bf16x8 vv  = *(const bf16x8*)(src + 3072);
            *(bf16x8*)(&Kl[krow * LDK + tcol])  = kv;
            *(bf16x8*)(&K2l[krow * LDK + tcol]) = k2v;
            #pragma unroll
            for (int e = 0; e < 8; ++e) Vt[(tcol + e) * LDK + krow] = vv[e];
        }
        __syncthreads();

        f32x4 s1[4] = {}, s2[4] = {};
        #pragma unroll
        for (int nf = 0; nf < 4; ++nf) {
            bf16x8 kb0 = *(const bf16x8*)(&Kl[(nf * 16 + l15) * LDK + lhi * 8]);
            s1[nf] = MFMA16(qa0, kb0, s1[nf]);
            bf16x8 kb1 = *(const bf16x8*)(&Kl[(nf * 16 + l15) * LDK + 32 + lhi * 8]);
            s1[nf] = MFMA16(qa1, kb1, s1[nf]);
            bf16x8 k2b0 = *(const bf16x8*)(&K2l[(nf * 16 + l15) * LDK + lhi * 8]);
            s2[nf] = MFMA16(q2a0, k2b0, s2[nf]);
            bf16x8 k2b1 = *(const bf16x8*)(&K2l[(nf * 16 + l15) * LDK + 32 + lhi * 8]);
            s2[nf] = MFMA16(q2a1, k2b1, s2[nf]);
        }

        #pragma unroll
        for (int nf = 0; nf < 4; ++nf) {
            #pragma unroll
            for (int r = 0; r < 4; ++r) {
                int qg = q0w + lhi * 4 + r;
                int kg = kt * 64 + nf * 16 + l15;
                float p = (kg <= qg) ? s1[nf][r] * s2[nf][r] * (1.0f / 4096.0f) : 0.0f;
                Pl[wave][(lhi * 4 + r) * LDK + nf * 16 + l15] = (bf16)p;
            }
        }

        #pragma unroll
        for (int kk = 0; kk < 2; ++kk) {
            bf16x8 pa = *(const bf16x8*)(&Pl[wave][l15 * LDK + kk * 32 + lhi * 8]);
            #pragma unroll
            for (int f = 0; f < 4; ++f) {
                bf16x8 vb = *(const bf16x8*)(&Vt[(f * 16 + l15) * LDK + kk * 32 + lhi * 8]);
                zacc[f] = MFMA16(pa, vb, zacc[f]);
            }
        }
    }

    #pragma unroll
    for (int f = 0; f < 4; ++f) {
        #pragma unroll
        for (int r = 0; r < 4; ++r) {
            atomicAdd(&z[(long)(q0w + lhi * 4 + r) * CC + h * DHEAD + f * 16 + l15], zacc[f][r]);
        }
    }
}

// ---------------------------------------------------------------------------
extern "C" void kernel_launch(void* const* d_in, const int* in_sizes, int n_in,
                              void* d_out, int out_size, void* d_ws, size_t ws_size,
                              hipStream_t stream) {
    const float* x   = (const float*)d_in[0];
    const float* Wq  = (const float*)d_in[1];
    const float* Wk  = (const float*)d_in[2];
    const float* Wq2 = (const float*)d_in[3];
    const float* Wk2 = (const float*)d_in[4];
    const float* Wv  = (const float*)d_in[5];
    const float* Wo  = (const float*)d_in[6];
    const float* Wp1 = (const float*)d_in[7];
    const float* Wp2 = (const float*)d_in[8];
    const float* Wd  = (const float*)d_in[9];
    const float* bd  = (const float*)d_in[10];

    char* ws = (char*)d_ws;
    size_t off = 0;
    auto alloc = [&](size_t bytes) {
        void* p = ws + off;
        off += (bytes + 255) & ~(size_t)255;
        return p;
    };
    // Total = 41.3 MB. zbuf (fp32, 6.29 MB) aliases hid (12.58 MB): zbuf is
    // dead after the Wo GEMM; hid is written only after that.
    float* xmid  = (float*)alloc(2048l * 768 * 4);
    bf16*  h2    = (bf16*)alloc(2048l * 768 * 2);
    bf16*  hid   = (bf16*)alloc(2048l * 3072 * 2);
    bf16*  h1    = (bf16*)alloc(2048l * 768 * 2);
    float* cosT  = (float*)alloc(2048l * 32 * 4);
    float* sinT  = (float*)alloc(2048l * 32 * 4);
    bf16*  qkv   = (bf16*)alloc(2048l * 3840 * 2);
    float* zbuf  = (float*)hid;   // alias

    BPtrs BQKV = {{Wq, Wk, Wq2, Wk2, Wv}};
    BPtrs BWO  = {{Wo, Wo, Wo, Wo, Wo}};
    BPtrs BWD  = {{Wd, Wd, Wd, Wd, Wd}};

    rope_table<<<dim3(256), 256, 0, stream>>>(cosT, sinT);
    rmsnorm<<<dim3(2048), 256, 0, stream>>>(x, h1);
    gemm_bt<0, false><<<dim3(16, 30), 256, 0, stream>>>(h1, BQKV, 768, qkv, nullptr, nullptr, nullptr, 2048, 3840, 768);
    rope_apply<<<dim3(2048), 256, 0, stream>>>(qkv, cosT, sinT);
    zero_f32<<<dim3(1536), 256, 0, stream>>>(zbuf);
    attn<<<dim3(32, 12, 4), 256, 0, stream>>>(qkv, zbuf);
    gemm_bt<1, true><<<dim3(16, 6), 256, 0, stream>>>(zbuf, BWO, 768, nullptr, xmid, x, nullptr, 2048, 768, 768);
    rmsnorm<<<dim3(2048), 256, 0, stream>>>(xmid, h2);
    gemm_mlp_up<<<dim3(16, 24), 256, 0, stream>>>(h2, Wp1, Wp2, hid, 2048, 3072, 768);
    gemm_bt<2, false><<<dim3(16, 6), 256, 0, stream>>>(hid, BWD, 768, nullptr, (float*)d_out, xmid, bd, 2048, 768, 3072);
}

// Round 7
// 315.687 us; speedup vs baseline: 1.2244x; 1.1163x over previous
//
#include <hip/hip_runtime.h>
#include <hip/hip_bf16.h>

typedef __bf16 bf16;
typedef bf16 bf16x8 __attribute__((ext_vector_type(8)));
typedef float f32x4 __attribute__((ext_vector_type(4)));

#define MFMA16(a, b, c) __builtin_amdgcn_mfma_f32_16x16x32_bf16((a), (b), (c), 0, 0, 0)

// Problem constants
static constexpr int TT    = 2048;
static constexpr int CC    = 768;
static constexpr int NHEAD = 12;
static constexpr int DHEAD = 64;

__device__ inline bf16x8 cvt8(const float4& a, const float4& b) {
    bf16x8 o;
    o[0] = (bf16)a.x; o[1] = (bf16)a.y; o[2] = (bf16)a.z; o[3] = (bf16)a.w;
    o[4] = (bf16)b.x; o[5] = (bf16)b.y; o[6] = (bf16)b.z; o[7] = (bf16)b.w;
    return o;
}

struct BPtrs { const float* p[5]; };

// ---------------------------------------------------------------------------
__global__ __launch_bounds__(256) void zero_f32(float* __restrict__ p) {
    int i = (blockIdx.x * 256 + threadIdx.x) * 4;
    *(f32x4*)(p + i) = f32x4{0.f, 0.f, 0.f, 0.f};
}

// d_out init: out = xmid + bd (bias broadcast over rows of 768)
__global__ __launch_bounds__(256) void init_bias(const float* __restrict__ xmid,
                                                 const float* __restrict__ bd,
                                                 float* __restrict__ out) {
    int i4 = (blockIdx.x * 256 + threadIdx.x) * 4;
    int col = i4 % CC;
    float4 a = *(const float4*)(xmid + i4);
    float4 b = *(const float4*)(bd + col);
    *(float4*)(out + i4) = float4{a.x + b.x, a.y + b.y, a.z + b.z, a.w + b.w};
}

// ---------------------------------------------------------------------------
// RoPE cos/sin tables: [2048][32] each, fp32
// ---------------------------------------------------------------------------
__global__ __launch_bounds__(256) void rope_table(float* __restrict__ cosT, float* __restrict__ sinT) {
    int i = blockIdx.x * 256 + threadIdx.x;   // 65536
    int t = i >> 5, j = i & 31;
    float inv = 1.0f / powf(10000.0f, (float)(2 * j) / 64.0f);
    float f = (float)t * inv;
    cosT[i] = cosf(f);
    sinT[i] = sinf(f);
}

// ---------------------------------------------------------------------------
// RMSNorm row kernel: 768 floats per row, 256 threads/block
// ---------------------------------------------------------------------------
__global__ __launch_bounds__(256) void rmsnorm(const float* __restrict__ x, bf16* __restrict__ out) {
    int row = blockIdx.x;
    const float* xr = x + (long)row * CC;
    int tid = threadIdx.x;
    float v0 = xr[tid], v1 = xr[tid + 256], v2 = xr[tid + 512];
    float ss = v0 * v0 + v1 * v1 + v2 * v2;
    #pragma unroll
    for (int off = 32; off > 0; off >>= 1) ss += __shfl_down(ss, off);
    __shared__ float red[4];
    if ((tid & 63) == 0) red[tid >> 6] = ss;
    __syncthreads();
    float tot = red[0] + red[1] + red[2] + red[3];
    float sc = rsqrtf(tot * (1.0f / 768.0f) + 1e-6f);
    bf16* o = out + (long)row * CC;
    o[tid]       = (bf16)(v0 * sc);
    o[tid + 256] = (bf16)(v1 * sc);
    o[tid + 512] = (bf16)(v2 * sc);
}

// ---------------------------------------------------------------------------
// GEMM: C[M,N] = A[M,K] @ B[N,K]^T.  A bf16 (fp32 if AF32); B fp32 (cvt in
// staging). B split into vertical parts (BPtrs). Tiles: BM x BN, 4 waves.
//   BN==128: waves 2x2, wave tile (BM/2)x64;  BN==64: waves 4x1, (BM/4)x64.
// Split-K: gridDim.z=SK, contiguous K chunks; EPI 3 atomically accumulates.
// EPI 0: outb = bf16(acc)
// EPI 1: outf = res + acc
// EPI 2: outf = res + bias + acc
// EPI 3: atomicAdd(outf, acc)
// ---------------------------------------------------------------------------
template <int EPI, bool AF32, int BM, int BN, int SK>
__global__ __launch_bounds__(256) void gemm_bt(
    const void* __restrict__ Av, BPtrs Bp, int partRows,
    bf16* __restrict__ outb, float* __restrict__ outf,
    const float* __restrict__ res, const float* __restrict__ bias,
    int M, int N, int K)
{
    constexpr int LDR = 40;               // LDS row stride (pad 32->40)
    constexpr int WC  = BN / 64;          // wave cols (1 or 2)
    constexpr int WR  = 4 / WC;           // wave rows
    constexpr int FM  = BM / (WR * 16);   // 16-row frags per wave
    constexpr int RA  = BM / 64;          // A staging chunks
    constexpr int RB  = BN / 64;          // B staging chunks
    __shared__ bf16 Al[BM * LDR];
    __shared__ bf16 Bl[BN * LDR];

    const int tid  = threadIdx.x;
    const int lane = tid & 63;
    const int wave = tid >> 6;
    const int wr = wave / WC, wc = wave % WC;
    const int l15 = lane & 15, lhi = lane >> 4;
    const int bm = blockIdx.x * BM, bn = blockIdx.y * BN;

    const int seg = bn / partRows;
    const float* Bbase = Bp.p[seg] + (long)(bn - seg * partRows) * K;

    const int srow = tid >> 2;          // 0..63
    const int scol = (tid & 3) * 8;     // 0,8,16,24

    const int kchunk = K / SK;
    const int koff   = (SK > 1) ? blockIdx.z * kchunk : 0;

    const bf16*  Ag  = (const bf16*)Av  + (long)(bm + srow) * K + koff + scol;
    const float* Agf = (const float*)Av + (long)(bm + srow) * K + koff + scol;
    const float* Bg  = Bbase + (long)srow * K + koff + scol;

    f32x4 acc[FM][4] = {};

    const int nk = kchunk / 32;
    bf16x8 ga[RA];
    float4 fa[RA][2];
    float4 fb[RB][2];
    #pragma unroll
    for (int i = 0; i < RA; ++i) {
        if constexpr (AF32) {
            fa[i][0] = *(const float4*)(Agf + (long)i * 64 * K);
            fa[i][1] = *(const float4*)(Agf + (long)i * 64 * K + 4);
        } else {
            ga[i] = *(const bf16x8*)(Ag + (long)i * 64 * K);
        }
    }
    #pragma unroll
    for (int i = 0; i < RB; ++i) {
        fb[i][0] = *(const float4*)(Bg + (long)i * 64 * K);
        fb[i][1] = *(const float4*)(Bg + (long)i * 64 * K + 4);
    }

    for (int t = 0; t < nk; ++t) {
        __syncthreads();
        #pragma unroll
        for (int i = 0; i < RA; ++i) {
            if constexpr (AF32)
                *(bf16x8*)(&Al[(srow + i * 64) * LDR + scol]) = cvt8(fa[i][0], fa[i][1]);
            else
                *(bf16x8*)(&Al[(srow + i * 64) * LDR + scol]) = ga[i];
        }
        #pragma unroll
        for (int i = 0; i < RB; ++i)
            *(bf16x8*)(&Bl[(srow + i * 64) * LDR + scol]) = cvt8(fb[i][0], fb[i][1]);
        __syncthreads();
        if (t + 1 < nk) {
            #pragma unroll
            for (int i = 0; i < RA; ++i) {
                if constexpr (AF32) {
                    const float* An = Agf + (t + 1) * 32 + (long)i * 64 * K;
                    fa[i][0] = *(const float4*)(An);
                    fa[i][1] = *(const float4*)(An + 4);
                } else {
                    ga[i] = *(const bf16x8*)(Ag + (t + 1) * 32 + (long)i * 64 * K);
                }
            }
            #pragma unroll
            for (int i = 0; i < RB; ++i) {
                const float* Bn = Bg + (t + 1) * 32 + (long)i * 64 * K;
                fb[i][0] = *(const float4*)(Bn);
                fb[i][1] = *(const float4*)(Bn + 4);
            }
        }
        bf16x8 a[FM], b[4];
        #pragma unroll
        for (int m = 0; m < FM; ++m)
            a[m] = *(const bf16x8*)(&Al[(wr * FM * 16 + m * 16 + l15) * LDR + lhi * 8]);
        #pragma unroll
        for (int n = 0; n < 4; ++n)
            b[n] = *(const bf16x8*)(&Bl[(wc * 64 + n * 16 + l15) * LDR + lhi * 8]);
        #pragma unroll
        for (int m = 0; m < FM; ++m)
            #pragma unroll
            for (int n = 0; n < 4; ++n)
                acc[m][n] = MFMA16(a[m], b[n], acc[m][n]);
    }

    #pragma unroll
    for (int m = 0; m < FM; ++m) {
        #pragma unroll
        for (int n = 0; n < 4; ++n) {
            int row0 = bm + wr * FM * 16 + m * 16 + lhi * 4;
            int col  = bn + wc * 64 + n * 16 + l15;
            #pragma unroll
            for (int r = 0; r < 4; ++r) {
                long idx = (long)(row0 + r) * N + col;
                float v = acc[m][n][r];
                if (EPI == 0) {
                    outb[idx] = (bf16)v;
                } else if (EPI == 1) {
                    outf[idx] = res[idx] + v;
                } else if (EPI == 2) {
                    outf[idx] = res[idx] + bias[col] + v;
                } else {
                    atomicAdd(&outf[idx], v);
                }
            }
        }
    }
}

// ---------------------------------------------------------------------------
// Fused MLP-up: hid = (A@B1^T) * (A@B2^T). 64x128 tile, 4 waves 2x2.
// ---------------------------------------------------------------------------
__global__ __launch_bounds__(256) void gemm_mlp_up(
    const bf16* __restrict__ A, const float* __restrict__ B1, const float* __restrict__ B2,
    bf16* __restrict__ out, int M, int N, int K)
{
    constexpr int LDR = 40;
    __shared__ bf16 Al[64 * LDR];
    __shared__ bf16 B1l[128 * LDR];
    __shared__ bf16 B2l[128 * LDR];

    const int tid  = threadIdx.x;
    const int lane = tid & 63;
    const int wave = tid >> 6;
    const int wr = wave >> 1, wc = wave & 1;
    const int l15 = lane & 15, lhi = lane >> 4;
    const int bm = blockIdx.x * 64, bn = blockIdx.y * 128;

    const int srow = tid >> 2;
    const int scol = (tid & 3) * 8;

    const bf16*  Ag  = A  + (long)(bm + srow) * K + scol;
    const float* B1g = B1 + (long)(bn + srow) * K + scol;
    const float* B2g = B2 + (long)(bn + srow) * K + scol;

    f32x4 acc1[2][4] = {};
    f32x4 acc2[2][4] = {};

    const int nk = K / 32;
    bf16x8 ga0 = *(const bf16x8*)(Ag);
    float4 g1a0 = *(const float4*)(B1g),               g1b0 = *(const float4*)(B1g + 4);
    float4 g1a1 = *(const float4*)(B1g + (long)64 * K), g1b1 = *(const float4*)(B1g + (long)64 * K + 4);
    float4 g2a0 = *(const float4*)(B2g),               g2b0 = *(const float4*)(B2g + 4);
    float4 g2a1 = *(const float4*)(B2g + (long)64 * K), g2b1 = *(const float4*)(B2g + (long)64 * K + 4);

    for (int t = 0; t < nk; ++t) {
        __syncthreads();
        *(bf16x8*)(&Al[srow * LDR + scol])         = ga0;
        *(bf16x8*)(&B1l[srow * LDR + scol])        = cvt8(g1a0, g1b0);
        *(bf16x8*)(&B1l[(srow + 64) * LDR + scol]) = cvt8(g1a1, g1b1);
        *(bf16x8*)(&B2l[srow * LDR + scol])        = cvt8(g2a0, g2b0);
        *(bf16x8*)(&B2l[(srow + 64) * LDR + scol]) = cvt8(g2a1, g2b1);
        __syncthreads();
        if (t + 1 < nk) {
            const bf16*  An  = Ag  + (t + 1) * 32;
            const float* B1n = B1g + (t + 1) * 32;
            const float* B2n = B2g + (t + 1) * 32;
            ga0 = *(const bf16x8*)(An);
            g1a0 = *(const float4*)(B1n);                g1b0 = *(const float4*)(B1n + 4);
            g1a1 = *(const float4*)(B1n + (long)64 * K); g1b1 = *(const float4*)(B1n + (long)64 * K + 4);
            g2a0 = *(const float4*)(B2n);                g2b0 = *(const float4*)(B2n + 4);
            g2a1 = *(const float4*)(B2n + (long)64 * K); g2b1 = *(const float4*)(B2n + (long)64 * K + 4);
        }
        bf16x8 a[2], b1[4], b2[4];
        #pragma unroll
        for (int m = 0; m < 2; ++m)
            a[m] = *(const bf16x8*)(&Al[(wr * 32 + m * 16 + l15) * LDR + lhi * 8]);
        #pragma unroll
        for (int n = 0; n < 4; ++n) {
            b1[n] = *(const bf16x8*)(&B1l[(wc * 64 + n * 16 + l15) * LDR + lhi * 8]);
            b2[n] = *(const bf16x8*)(&B2l[(wc * 64 + n * 16 + l15) * LDR + lhi * 8]);
        }
        #pragma unroll
        for (int m = 0; m < 2; ++m)
            #pragma unroll
            for (int n = 0; n < 4; ++n) {
                acc1[m][n] = MFMA16(a[m], b1[n], acc1[m][n]);
                acc2[m][n] = MFMA16(a[m], b2[n], acc2[m][n]);
            }
    }

    #pragma unroll
    for (int m = 0; m < 2; ++m) {
        #pragma unroll
        for (int n = 0; n < 4; ++n) {
            int row0 = bm + wr * 32 + m * 16 + lhi * 4;
            int col  = bn + wc * 64 + n * 16 + l15;
            #pragma unroll
            for (int r = 0; r < 4; ++r) {
                out[(long)(row0 + r) * N + col] = (bf16)(acc1[m][n][r] * acc2[m][n][r]);
            }
        }
    }
}

// ---------------------------------------------------------------------------
// In-place RoPE on q,k,q2,k2 (cols 0..3071 of qkv[t][3840])
// ---------------------------------------------------------------------------
__global__ __launch_bounds__(256) void rope_apply(bf16* __restrict__ qkv,
                                                  const float* __restrict__ cosT,
                                                  const float* __restrict__ sinT) {
    int t = blockIdx.x;
    for (int it = threadIdx.x; it < 4 * NHEAD * 32; it += 256) {
        int mat = it / (NHEAD * 32);
        int rem = it % (NHEAD * 32);
        int hh = rem / 32, j = rem % 32;
        long base = (long)t * 3840 + mat * CC + hh * DHEAD + j;
        float c = cosT[t * 32 + j], s = sinT[t * 32 + j];
        float x1 = (float)qkv[base], x2 = (float)qkv[base + 32];
        qkv[base]      = (bf16)(x1 * c + x2 * s);
        qkv[base + 32] = (bf16)(-x1 * s + x2 * c);
    }
}

// ---------------------------------------------------------------------------
// Split-K causal quadratic-gated attention (fp32 atomicAdd accumulate)
// ---------------------------------------------------------------------------
__global__ __launch_bounds__(256) void attn(const bf16* __restrict__ qkv, float* __restrict__ z) {
    constexpr int LDK = 72;
    __shared__ bf16 Kl[64 * LDK];
    __shared__ bf16 K2l[64 * LDK];
    __shared__ bf16 Vt[64 * LDK];       // Vt[d][k]
    __shared__ bf16 Pl[4][16 * LDK];    // per-wave P tile [16 q][64 k]

    const int qt = blockIdx.x, h = blockIdx.y, s = blockIdx.z;
    const int nkt  = qt + 1;
    const int base = nkt >> 2, rem = nkt & 3;
    const int len  = base + (s < rem ? 1 : 0);
    if (len == 0) return;                       // uniform per block
    const int k0 = s * base + min(s, rem);

    const int tid = threadIdx.x, lane = tid & 63, wave = tid >> 6;
    const int l15 = lane & 15, lhi = lane >> 4;
    const int q0w = qt * 64 + wave * 16;

    const bf16* qbase = qkv + (long)(q0w + l15) * 3840 + h * DHEAD + lhi * 8;
    const bf16x8 qa0  = *(const bf16x8*)(qbase);
    const bf16x8 qa1  = *(const bf16x8*)(qbase + 32);
    const bf16x8 q2a0 = *(const bf16x8*)(qbase + 1536);
    const bf16x8 q2a1 = *(const bf16x8*)(qbase + 1536 + 32);

    f32x4 zacc[4] = {};

    const int trow = tid >> 3;        // 0..31
    const int tcol = (tid & 7) * 8;   // 0..56

    for (int kt = k0; kt < k0 + len; ++kt) {
        __syncthreads();
        #pragma unroll
        for (int r2 = 0; r2 < 2; ++r2) {
            int krow = r2 * 32 + trow;
            const bf16* src = qkv + (long)(kt * 64 + krow) * 3840 + h * DHEAD + tcol;
            bf16x8 kv  = *(const bf16x8*)(src + 768);
            bf16x8 k2v = *(const bf16x8*)(src + 2304);
            bf16x8 vv  = *(const bf16x8*)(src + 3072);
            *(bf16x8*)(&Kl[krow * LDK + tcol])  = kv;
            *(bf16x8*)(&K2l[krow * LDK + tcol]) = k2v;
            #pragma unroll
            for (int e = 0; e < 8; ++e) Vt[(tcol + e) * LDK + krow] = vv[e];
        }
        __syncthreads();

        f32x4 s1[4] = {}, s2[4] = {};
        #pragma unroll
        for (int nf = 0; nf < 4; ++nf) {
            bf16x8 kb0 = *(const bf16x8*)(&Kl[(nf * 16 + l15) * LDK + lhi * 8]);
            s1[nf] = MFMA16(qa0, kb0, s1[nf]);
            bf16x8 kb1 = *(const bf16x8*)(&Kl[(nf * 16 + l15) * LDK + 32 + lhi * 8]);
            s1[nf] = MFMA16(qa1, kb1, s1[nf]);
            bf16x8 k2b0 = *(const bf16x8*)(&K2l[(nf * 16 + l15) * LDK + lhi * 8]);
            s2[nf] = MFMA16(q2a0, k2b0, s2[nf]);
            bf16x8 k2b1 = *(const bf16x8*)(&K2l[(nf * 16 + l15) * LDK + 32 + lhi * 8]);
            s2[nf] = MFMA16(q2a1, k2b1, s2[nf]);
        }

        #pragma unroll
        for (int nf = 0; nf < 4; ++nf) {
            #pragma unroll
            for (int r = 0; r < 4; ++r) {
                int qg = q0w + lhi * 4 + r;
                int kg = kt * 64 + nf * 16 + l15;
                float p = (kg <= qg) ? s1[nf][r] * s2[nf][r] * (1.0f / 4096.0f) : 0.0f;
                Pl[wave][(lhi * 4 + r) * LDK + nf * 16 + l15] = (bf16)p;
            }
        }

        #pragma unroll
        for (int kk = 0; kk < 2; ++kk) {
            bf16x8 pa = *(const bf16x8*)(&Pl[wave][l15 * LDK + kk * 32 + lhi * 8]);
            #pragma unroll
            for (int f = 0; f < 4; ++f) {
                bf16x8 vb = *(const bf16x8*)(&Vt[(f * 16 + l15) * LDK + kk * 32 + lhi * 8]);
                zacc[f] = MFMA16(pa, vb, zacc[f]);
            }
        }
    }

    #pragma unroll
    for (int f = 0; f < 4; ++f) {
        #pragma unroll
        for (int r = 0; r < 4; ++r) {
            atomicAdd(&z[(long)(q0w + lhi * 4 + r) * CC + h * DHEAD + f * 16 + l15], zacc[f][r]);
        }
    }
}

// ---------------------------------------------------------------------------
extern "C" void kernel_launch(void* const* d_in, const int* in_sizes, int n_in,
                              void* d_out, int out_size, void* d_ws, size_t ws_size,
                              hipStream_t stream) {
    const float* x   = (const float*)d_in[0];
    const float* Wq  = (const float*)d_in[1];
    const float* Wk  = (const float*)d_in[2];
    const float* Wq2 = (const float*)d_in[3];
    const float* Wk2 = (const float*)d_in[4];
    const float* Wv  = (const float*)d_in[5];
    const float* Wo  = (const float*)d_in[6];
    const float* Wp1 = (const float*)d_in[7];
    const float* Wp2 = (const float*)d_in[8];
    const float* Wd  = (const float*)d_in[9];
    const float* bd  = (const float*)d_in[10];

    char* ws = (char*)d_ws;
    size_t off = 0;
    auto alloc = [&](size_t bytes) {
        void* p = ws + off;
        off += (bytes + 255) & ~(size_t)255;
        return p;
    };
    // Total = 41.3 MB. zbuf (fp32) aliases hid (dead after Wo GEMM).
    float* xmid  = (float*)alloc(2048l * 768 * 4);
    bf16*  h2    = (bf16*)alloc(2048l * 768 * 2);
    bf16*  hid   = (bf16*)alloc(2048l * 3072 * 2);
    bf16*  h1    = (bf16*)alloc(2048l * 768 * 2);
    float* cosT  = (float*)alloc(2048l * 32 * 4);
    float* sinT  = (float*)alloc(2048l * 32 * 4);
    bf16*  qkv   = (bf16*)alloc(2048l * 3840 * 2);
    float* zbuf  = (float*)hid;   // alias

    BPtrs BQKV = {{Wq, Wk, Wq2, Wk2, Wv}};
    BPtrs BWO  = {{Wo, Wo, Wo, Wo, Wo}};
    BPtrs BWD  = {{Wd, Wd, Wd, Wd, Wd}};

    rope_table<<<dim3(256), 256, 0, stream>>>(cosT, sinT);
    rmsnorm<<<dim3(2048), 256, 0, stream>>>(x, h1);
    // qkv: 64x128 tiles -> 960 blocks
    gemm_bt<0, false, 64, 128, 1><<<dim3(32, 30), 256, 0, stream>>>(
        h1, BQKV, 768, qkv, nullptr, nullptr, nullptr, 2048, 3840, 768);
    rope_apply<<<dim3(2048), 256, 0, stream>>>(qkv, cosT, sinT);
    zero_f32<<<dim3(1536), 256, 0, stream>>>(zbuf);
    attn<<<dim3(32, 12, 4), 256, 0, stream>>>(qkv, zbuf);
    // xmid = x, then Wo split-K atomic accumulate: 64x64, SK=2 -> 768 blocks
    hipMemcpyAsync(xmid, x, 2048l * 768 * 4, hipMemcpyDeviceToDevice, stream);
    gemm_bt<3, true, 64, 64, 2><<<dim3(32, 12, 2), 256, 0, stream>>>(
        zbuf, BWO, 768, nullptr, xmid, nullptr, nullptr, 2048, 768, 768);
    rmsnorm<<<dim3(2048), 256, 0, stream>>>(xmid, h2);
    // MLP up: 64x128 tiles -> 768 blocks
    gemm_mlp_up<<<dim3(32, 24), 256, 0, stream>>>(h2, Wp1, Wp2, hid, 2048, 3072, 768);
    // d_out = xmid + bd, then Wd split-K atomic accumulate: 64x64, SK=2 -> 768 blocks
    init_bias<<<dim3(1536), 256, 0, stream>>>(xmid, bd, (float*)d_out);
    gemm_bt<3, false, 64, 64, 2><<<dim3(32, 12, 2), 256, 0, stream>>>(
        hid, BWD, 768, nullptr, (float*)d_out, nullptr, nullptr, 2048, 768, 3072);
}

// Round 8
// 281.966 us; speedup vs baseline: 1.3708x; 1.1196x over previous
//
#include <hip/hip_runtime.h>
#include <hip/hip_bf16.h>

typedef __bf16 bf16;
typedef bf16 bf16x8 __attribute__((ext_vector_type(8)));
typedef float f32x4 __attribute__((ext_vector_type(4)));

#define MFMA16(a, b, c) __builtin_amdgcn_mfma_f32_16x16x32_bf16((a), (b), (c), 0, 0, 0)

static constexpr int TT    = 2048;
static constexpr int CC    = 768;
static constexpr int NHEAD = 12;
static constexpr int DHEAD = 64;

__device__ inline bf16x8 cvt8(const float4& a, const float4& b) {
    bf16x8 o;
    o[0] = (bf16)a.x; o[1] = (bf16)a.y; o[2] = (bf16)a.z; o[3] = (bf16)a.w;
    o[4] = (bf16)b.x; o[5] = (bf16)b.y; o[6] = (bf16)b.z; o[7] = (bf16)b.w;
    return o;
}

struct BPtrs { const float* p[5]; };

// ---------------------------------------------------------------------------
__global__ __launch_bounds__(256) void zero_f32(float* __restrict__ p) {
    int i = (blockIdx.x * 256 + threadIdx.x) * 4;
    *(f32x4*)(p + i) = f32x4{0.f, 0.f, 0.f, 0.f};
}

__global__ __launch_bounds__(256) void init_bias(const float* __restrict__ xmid,
                                                 const float* __restrict__ bd,
                                                 float* __restrict__ out) {
    int i4 = (blockIdx.x * 256 + threadIdx.x) * 4;
    int col = i4 % CC;
    float4 a = *(const float4*)(xmid + i4);
    float4 b = *(const float4*)(bd + col);
    *(float4*)(out + i4) = float4{a.x + b.x, a.y + b.y, a.z + b.z, a.w + b.w};
}

// ---------------------------------------------------------------------------
__global__ __launch_bounds__(256) void rope_table(float* __restrict__ cosT, float* __restrict__ sinT) {
    int i = blockIdx.x * 256 + threadIdx.x;   // 65536
    int t = i >> 5, j = i & 31;
    float inv = 1.0f / powf(10000.0f, (float)(2 * j) / 64.0f);
    float f = (float)t * inv;
    cosT[i] = cosf(f);
    sinT[i] = sinf(f);
}

// ---------------------------------------------------------------------------
__global__ __launch_bounds__(256) void rmsnorm(const float* __restrict__ x, bf16* __restrict__ out) {
    int row = blockIdx.x;
    const float* xr = x + (long)row * CC;
    int tid = threadIdx.x;
    float v0 = xr[tid], v1 = xr[tid + 256], v2 = xr[tid + 512];
    float ss = v0 * v0 + v1 * v1 + v2 * v2;
    #pragma unroll
    for (int off = 32; off > 0; off >>= 1) ss += __shfl_down(ss, off);
    __shared__ float red[4];
    if ((tid & 63) == 0) red[tid >> 6] = ss;
    __syncthreads();
    float tot = red[0] + red[1] + red[2] + red[3];
    float sc = rsqrtf(tot * (1.0f / 768.0f) + 1e-6f);
    bf16* o = out + (long)row * CC;
    o[tid]       = (bf16)(v0 * sc);
    o[tid + 256] = (bf16)(v1 * sc);
    o[tid + 512] = (bf16)(v2 * sc);
}

// ---------------------------------------------------------------------------
// GEMM: C[M,N] = A[M,K] @ B[N,K]^T.  A bf16 (fp32 if AF32); B fp32 cvt in
// staging. BK=64 (one barrier pair per 64-K). 4 waves.
//   BN==128: waves 2x2; BN==64: waves 4x1. Staging chunk = 32 rows x 64 cols.
// EPI 0: outb=bf16(acc); 1: outf=res+acc; 2: outf=res+bias+acc; 3: atomicAdd.
// ---------------------------------------------------------------------------
template <int EPI, bool AF32, int BM, int BN, int SK>
__global__ __launch_bounds__(256) void gemm_bt(
    const void* __restrict__ Av, BPtrs Bp, int partRows,
    bf16* __restrict__ outb, float* __restrict__ outf,
    const float* __restrict__ res, const float* __restrict__ bias,
    int M, int N, int K)
{
    constexpr int BK = 64, LDR = 72;
    constexpr int WC = BN / 64, WR = 4 / WC, FM = BM / (WR * 16);
    constexpr int RA = BM / 32, RB = BN / 32;
    __shared__ bf16 Al[BM * LDR];
    __shared__ bf16 Bl[BN * LDR];

    const int tid = threadIdx.x, lane = tid & 63, wave = tid >> 6;
    const int wr = wave / WC, wc = wave % WC;
    const int l15 = lane & 15, lhi = lane >> 4;
    const int bm = blockIdx.x * BM, bn = blockIdx.y * BN;
    const int seg = bn / partRows;
    const float* Bbase = Bp.p[seg] + (long)(bn - seg * partRows) * K;

    const int srow = tid >> 3;          // 0..31
    const int scol = (tid & 7) * 8;     // 0..56

    const int kchunk = K / SK;
    const int koff   = (SK > 1) ? blockIdx.z * kchunk : 0;

    const bf16*  Ag  = (const bf16*)Av  + (long)(bm + srow) * K + koff + scol;
    const float* Agf = (const float*)Av + (long)(bm + srow) * K + koff + scol;
    const float* Bg  = Bbase + (long)srow * K + koff + scol;

    f32x4 acc[FM][4] = {};
    const int nk = kchunk / BK;

    bf16x8 ga[RA];
    float4 fa[RA][2];
    float4 fb[RB][2];
    auto LOAD = [&](int t) {
        #pragma unroll
        for (int i = 0; i < RA; ++i) {
            if constexpr (AF32) {
                const float* p = Agf + (long)i * 32 * K + t * BK;
                fa[i][0] = *(const float4*)(p);
                fa[i][1] = *(const float4*)(p + 4);
            } else {
                ga[i] = *(const bf16x8*)(Ag + (long)i * 32 * K + t * BK);
            }
        }
        #pragma unroll
        for (int i = 0; i < RB; ++i) {
            const float* p = Bg + (long)i * 32 * K + t * BK;
            fb[i][0] = *(const float4*)(p);
            fb[i][1] = *(const float4*)(p + 4);
        }
    };
    LOAD(0);

    for (int t = 0; t < nk; ++t) {
        __syncthreads();
        #pragma unroll
        for (int i = 0; i < RA; ++i) {
            if constexpr (AF32)
                *(bf16x8*)(&Al[(srow + i * 32) * LDR + scol]) = cvt8(fa[i][0], fa[i][1]);
            else
                *(bf16x8*)(&Al[(srow + i * 32) * LDR + scol]) = ga[i];
        }
        #pragma unroll
        for (int i = 0; i < RB; ++i)
            *(bf16x8*)(&Bl[(srow + i * 32) * LDR + scol]) = cvt8(fb[i][0], fb[i][1]);
        __syncthreads();
        if (t + 1 < nk) LOAD(t + 1);

        bf16x8 afr[FM][2], bfr[4][2];
        #pragma unroll
        for (int m = 0; m < FM; ++m)
            #pragma unroll
            for (int kk = 0; kk < 2; ++kk)
                afr[m][kk] = *(const bf16x8*)(&Al[(wr * FM * 16 + m * 16 + l15) * LDR + kk * 32 + lhi * 8]);
        #pragma unroll
        for (int n = 0; n < 4; ++n)
            #pragma unroll
            for (int kk = 0; kk < 2; ++kk)
                bfr[n][kk] = *(const bf16x8*)(&Bl[(wc * 64 + n * 16 + l15) * LDR + kk * 32 + lhi * 8]);
        #pragma unroll
        for (int kk = 0; kk < 2; ++kk)
            #pragma unroll
            for (int m = 0; m < FM; ++m)
                #pragma unroll
                for (int n = 0; n < 4; ++n)
                    acc[m][n] = MFMA16(afr[m][kk], bfr[n][kk], acc[m][n]);
    }

    #pragma unroll
    for (int m = 0; m < FM; ++m) {
        #pragma unroll
        for (int n = 0; n < 4; ++n) {
            int row0 = bm + wr * FM * 16 + m * 16 + lhi * 4;
            int col  = bn + wc * 64 + n * 16 + l15;
            #pragma unroll
            for (int r = 0; r < 4; ++r) {
                long idx = (long)(row0 + r) * N + col;
                float v = acc[m][n][r];
                if (EPI == 0) {
                    outb[idx] = (bf16)v;
                } else if (EPI == 1) {
                    outf[idx] = res[idx] + v;
                } else if (EPI == 2) {
                    outf[idx] = res[idx] + bias[col] + v;
                } else {
                    atomicAdd(&outf[idx], v);
                }
            }
        }
    }
}

// ---------------------------------------------------------------------------
// Fused MLP-up: hid = (A@B1^T) * (A@B2^T). 64x64 tile, BK=64, 4 waves 4x1.
// ---------------------------------------------------------------------------
__global__ __launch_bounds__(256) void gemm_mlp_up(
    const bf16* __restrict__ A, const float* __restrict__ B1, const float* __restrict__ B2,
    bf16* __restrict__ out, int M, int N, int K)
{
    constexpr int BK = 64, LDR = 72;
    __shared__ bf16 Al[64 * LDR];
    __shared__ bf16 B1l[64 * LDR];
    __shared__ bf16 B2l[64 * LDR];

    const int tid = threadIdx.x, lane = tid & 63, wave = tid >> 6;
    const int l15 = lane & 15, lhi = lane >> 4;
    const int bm = blockIdx.x * 64, bn = blockIdx.y * 64;

    const int srow = tid >> 3;
    const int scol = (tid & 7) * 8;

    const bf16*  Ag  = A  + (long)(bm + srow) * K + scol;
    const float* B1g = B1 + (long)(bn + srow) * K + scol;
    const float* B2g = B2 + (long)(bn + srow) * K + scol;

    f32x4 acc1[4] = {};
    f32x4 acc2[4] = {};
    const int nk = K / BK;

    bf16x8 ga[2];
    float4 f1[2][2], f2[2][2];
    auto LOAD = [&](int t) {
        #pragma unroll
        for (int i = 0; i < 2; ++i) {
            ga[i] = *(const bf16x8*)(Ag + (long)i * 32 * K + t * BK);
            const float* p1 = B1g + (long)i * 32 * K + t * BK;
            const float* p2 = B2g + (long)i * 32 * K + t * BK;
            f1[i][0] = *(const float4*)(p1); f1[i][1] = *(const float4*)(p1 + 4);
            f2[i][0] = *(const float4*)(p2); f2[i][1] = *(const float4*)(p2 + 4);
        }
    };
    LOAD(0);

    for (int t = 0; t < nk; ++t) {
        __syncthreads();
        #pragma unroll
        for (int i = 0; i < 2; ++i) {
            *(bf16x8*)(&Al[(srow + i * 32) * LDR + scol])  = ga[i];
            *(bf16x8*)(&B1l[(srow + i * 32) * LDR + scol]) = cvt8(f1[i][0], f1[i][1]);
            *(bf16x8*)(&B2l[(srow + i * 32) * LDR + scol]) = cvt8(f2[i][0], f2[i][1]);
        }
        __syncthreads();
        if (t + 1 < nk) LOAD(t + 1);

        bf16x8 a[2], b1[4][2], b2[4][2];
        #pragma unroll
        for (int kk = 0; kk < 2; ++kk)
            a[kk] = *(const bf16x8*)(&Al[(wave * 16 + l15) * LDR + kk * 32 + lhi * 8]);
        #pragma unroll
        for (int n = 0; n < 4; ++n)
            #pragma unroll
            for (int kk = 0; kk < 2; ++kk) {
                b1[n][kk] = *(const bf16x8*)(&B1l[(n * 16 + l15) * LDR + kk * 32 + lhi * 8]);
                b2[n][kk] = *(const bf16x8*)(&B2l[(n * 16 + l15) * LDR + kk * 32 + lhi * 8]);
            }
        #pragma unroll
        for (int kk = 0; kk < 2; ++kk)
            #pragma unroll
            for (int n = 0; n < 4; ++n) {
                acc1[n] = MFMA16(a[kk], b1[n][kk], acc1[n]);
                acc2[n] = MFMA16(a[kk], b2[n][kk], acc2[n]);
            }
    }

    #pragma unroll
    for (int n = 0; n < 4; ++n) {
        int row0 = bm + wave * 16 + lhi * 4;
        int col  = bn + n * 16 + l15;
        #pragma unroll
        for (int r = 0; r < 4; ++r)
            out[(long)(row0 + r) * N + col] = (bf16)(acc1[n][r] * acc2[n][r]);
    }
}

// ---------------------------------------------------------------------------
// Vectorized in-place RoPE. Block 192 threads: 4 mats x 12 heads x 4 j-octets.
// ---------------------------------------------------------------------------
__global__ __launch_bounds__(192) void rope_apply(bf16* __restrict__ qkv,
                                                  const float* __restrict__ cosT,
                                                  const float* __restrict__ sinT) {
    int t = blockIdx.x;
    int u = threadIdx.x;                 // 0..191
    int mat = u / 48, r = u % 48;
    int hh = r >> 2, j8 = r & 3;
    long base = (long)t * 3840 + mat * CC + hh * DHEAD + j8 * 8;
    bf16x8 x1 = *(const bf16x8*)(qkv + base);
    bf16x8 x2 = *(const bf16x8*)(qkv + base + 32);
    float cv[8], sv[8];
    *(float4*)&cv[0] = *(const float4*)(cosT + t * 32 + j8 * 8);
    *(float4*)&cv[4] = *(const float4*)(cosT + t * 32 + j8 * 8 + 4);
    *(float4*)&sv[0] = *(const float4*)(sinT + t * 32 + j8 * 8);
    *(float4*)&sv[4] = *(const float4*)(sinT + t * 32 + j8 * 8 + 4);
    bf16x8 o1, o2;
    #pragma unroll
    for (int e = 0; e < 8; ++e) {
        float a = (float)x1[e], b = (float)x2[e];
        o1[e] = (bf16)(a * cv[e] + b * sv[e]);
        o2[e] = (bf16)(-a * sv[e] + b * cv[e]);
    }
    *(bf16x8*)(qkv + base)      = o1;
    *(bf16x8*)(qkv + base + 32) = o2;
}

// ---------------------------------------------------------------------------
// Split-K causal quadratic-gated attention, longest-first, reg-prefetched.
//   z[q,h,:] += sum_{k chunk} (S1*S2/4096) * v[k,h,:]  (fp32 atomicAdd)
// grid (32, 12, 8): qt = 31-bx (longest blocks dispatch first).
// ---------------------------------------------------------------------------
__global__ __launch_bounds__(256) void attn(const bf16* __restrict__ qkv, float* __restrict__ z) {
    constexpr int LDK = 72, LDV = 66;   // LDV=66: Vt scatter 16-way -> ~4-way
    __shared__ bf16 Kl[64 * LDK];
    __shared__ bf16 K2l[64 * LDK];
    __shared__ bf16 Vt[64 * LDV];       // Vt[d][k]
    __shared__ bf16 Pl[4][16 * LDK];

    const int qt = 31 - blockIdx.x, h = blockIdx.y, s = blockIdx.z;
    const int nkt  = qt + 1;
    const int base = nkt >> 3, rem = nkt & 7;
    const int len  = base + (s < rem ? 1 : 0);
    if (len == 0) return;
    const int k0 = s * base + min(s, rem);

    const int tid = threadIdx.x, lane = tid & 63, wave = tid >> 6;
    const int l15 = lane & 15, lhi = lane >> 4;
    const int q0w = qt * 64 + wave * 16;

    const bf16* qbase = qkv + (long)(q0w + l15) * 3840 + h * DHEAD + lhi * 8;
    const bf16x8 qa0  = *(const bf16x8*)(qbase);
    const bf16x8 qa1  = *(const bf16x8*)(qbase + 32);
    const bf16x8 q2a0 = *(const bf16x8*)(qbase + 1536);
    const bf16x8 q2a1 = *(const bf16x8*)(qbase + 1536 + 32);

    f32x4 zacc[4] = {};

    const int trow = tid >> 3;        // 0..31
    const int tcol = (tid & 7) * 8;   // 0..56

    bf16x8 kvr[2], k2r[2], vvr[2];
    auto LOAD = [&](int kt) {
        #pragma unroll
        for (int r2 = 0; r2 < 2; ++r2) {
            const bf16* src = qkv + (long)(kt * 64 + r2 * 32 + trow) * 3840 + h * DHEAD + tcol;
            kvr[r2] = *(const bf16x8*)(src + 768);
            k2r[r2] = *(const bf16x8*)(src + 2304);
            vvr[r2] = *(const bf16x8*)(src + 3072);
        }
    };
    LOAD(k0);

    for (int kt = k0; kt < k0 + len; ++kt) {
        __syncthreads();
        #pragma unroll
        for (int r2 = 0; r2 < 2; ++r2) {
            int krow = r2 * 32 + trow;
            *(bf16x8*)(&Kl[krow * LDK + tcol])  = kvr[r2];
            *(bf16x8*)(&K2l[krow * LDK + tcol]) = k2r[r2];
            #pragma unroll
            for (int e = 0; e < 8; ++e) Vt[(tcol + e) * LDV + krow] = vvr[r2][e];
        }
        __syncthreads();
        if (kt + 1 < k0 + len) LOAD(kt + 1);

        f32x4 s1[4] = {}, s2[4] = {};
        #pragma unroll
        for (int nf = 0; nf < 4; ++nf) {
            bf16x8 kb0 = *(const bf16x8*)(&Kl[(nf * 16 + l15) * LDK + lhi * 8]);
            s1[nf] = MFMA16(qa0, kb0, s1[nf]);
            bf16x8 kb1 = *(const bf16x8*)(&Kl[(nf * 16 + l15) * LDK + 32 + lhi * 8]);
            s1[nf] = MFMA16(qa1, kb1, s1[nf]);
            bf16x8 k2b0 = *(const bf16x8*)(&K2l[(nf * 16 + l15) * LDK + lhi * 8]);
            s2[nf] = MFMA16(q2a0, k2b0, s2[nf]);
            bf16x8 k2b1 = *(const bf16x8*)(&K2l[(nf * 16 + l15) * LDK + 32 + lhi * 8]);
            s2[nf] = MFMA16(q2a1, k2b1, s2[nf]);
        }

        #pragma unroll
        for (int nf = 0; nf < 4; ++nf) {
            #pragma unroll
            for (int r = 0; r < 4; ++r) {
                int qg = q0w + lhi * 4 + r;
                int kg = kt * 64 + nf * 16 + l15;
                float p = (kg <= qg) ? s1[nf][r] * s2[nf][r] * (1.0f / 4096.0f) : 0.0f;
                Pl[wave][(lhi * 4 + r) * LDK + nf * 16 + l15] = (bf16)p;
            }
        }

        #pragma unroll
        for (int kk = 0; kk < 2; ++kk) {
            bf16x8 pa = *(const bf16x8*)(&Pl[wave][l15 * LDK + kk * 32 + lhi * 8]);
            #pragma unroll
            for (int f = 0; f < 4; ++f) {
                bf16x8 vb = *(const bf16x8*)(&Vt[(f * 16 + l15) * LDV + kk * 32 + lhi * 8]);
                zacc[f] = MFMA16(pa, vb, zacc[f]);
            }
        }
    }

    #pragma unroll
    for (int f = 0; f < 4; ++f) {
        #pragma unroll
        for (int r = 0; r < 4; ++r) {
            atomicAdd(&z[(long)(q0w + lhi * 4 + r) * CC + h * DHEAD + f * 16 + l15], zacc[f][r]);
        }
    }
}

// ---------------------------------------------------------------------------
extern "C" void kernel_launch(void* const* d_in, const int* in_sizes, int n_in,
                              void* d_out, int out_size, void* d_ws, size_t ws_size,
                              hipStream_t stream) {
    const float* x   = (const float*)d_in[0];
    const float* Wq  = (const float*)d_in[1];
    const float* Wk  = (const float*)d_in[2];
    const float* Wq2 = (const float*)d_in[3];
    const float* Wk2 = (const float*)d_in[4];
    const float* Wv  = (const float*)d_in[5];
    const float* Wo  = (const float*)d_in[6];
    const float* Wp1 = (const float*)d_in[7];
    const float* Wp2 = (const float*)d_in[8];
    const float* Wd  = (const float*)d_in[9];
    const float* bd  = (const float*)d_in[10];

    char* ws = (char*)d_ws;
    size_t off = 0;
    auto alloc = [&](size_t bytes) {
        void* p = ws + off;
        off += (bytes + 255) & ~(size_t)255;
        return p;
    };
    // Total = 41.3 MB. zbuf (fp32) aliases hid (dead after Wo GEMM).
    float* xmid  = (float*)alloc(2048l * 768 * 4);
    bf16*  h2    = (bf16*)alloc(2048l * 768 * 2);
    bf16*  hid   = (bf16*)alloc(2048l * 3072 * 2);
    bf16*  h1    = (bf16*)alloc(2048l * 768 * 2);
    float* cosT  = (float*)alloc(2048l * 32 * 4);
    float* sinT  = (float*)alloc(2048l * 32 * 4);
    bf16*  qkv   = (bf16*)alloc(2048l * 3840 * 2);
    float* zbuf  = (float*)hid;   // alias

    BPtrs BQKV = {{Wq, Wk, Wq2, Wk2, Wv}};
    BPtrs BWO  = {{Wo, Wo, Wo, Wo, Wo}};
    BPtrs BWD  = {{Wd, Wd, Wd, Wd, Wd}};

    rope_table<<<dim3(256), 256, 0, stream>>>(cosT, sinT);
    rmsnorm<<<dim3(2048), 256, 0, stream>>>(x, h1);
    // qkv: 64x128 tiles, BK=64 -> 960 blocks, 12 iters
    gemm_bt<0, false, 64, 128, 1><<<dim3(32, 30), 256, 0, stream>>>(
        h1, BQKV, 768, qkv, nullptr, nullptr, nullptr, 2048, 3840, 768);
    rope_apply<<<dim3(2048), 192, 0, stream>>>(qkv, cosT, sinT);
    zero_f32<<<dim3(1536), 256, 0, stream>>>(zbuf);
    // attn: longest-first, SK=8 -> 2736 valid blocks, <=4 iters each
    attn<<<dim3(32, 12, 8), 256, 0, stream>>>(qkv, zbuf);
    // xmid = x, then Wo split-K atomic accumulate: 64x64 BK=64, SK=2
    hipMemcpyAsync(xmid, x, 2048l * 768 * 4, hipMemcpyDeviceToDevice, stream);
    gemm_bt<3, true, 64, 64, 2><<<dim3(32, 12, 2), 256, 0, stream>>>(
        zbuf, BWO, 768, nullptr, xmid, nullptr, nullptr, 2048, 768, 768);
    rmsnorm<<<dim3(2048), 256, 0, stream>>>(xmid, h2);
    // MLP up: 64x64 tiles BK=64 -> 1536 blocks
    gemm_mlp_up<<<dim3(32, 48), 256, 0, stream>>>(h2, Wp1, Wp2, hid, 2048, 3072, 768);
    // d_out = xmid + bd, then Wd split-K atomic accumulate: 64x64 BK=64, SK=2
    init_bias<<<dim3(1536), 256, 0, stream>>>(xmid, bd, (float*)d_out);
    gemm_bt<3, false, 64, 64, 2><<<dim3(32, 12, 2), 256, 0, stream>>>(
        hid, BWD, 768, nullptr, (float*)d_out, nullptr, nullptr, 2048, 768, 3072);
}

// Round 9
// 250.168 us; speedup vs baseline: 1.5450x; 1.1271x over previous
//
#include <hip/hip_runtime.h>
#include <hip/hip_bf16.h>

typedef __bf16 bf16;
typedef bf16 bf16x8 __attribute__((ext_vector_type(8)));
typedef float f32x4 __attribute__((ext_vector_type(4)));

#define MFMA16(a, b, c) __builtin_amdgcn_mfma_f32_16x16x32_bf16((a), (b), (c), 0, 0, 0)

static constexpr int TT    = 2048;
static constexpr int CC    = 768;
static constexpr int NHEAD = 12;
static constexpr int DHEAD = 64;

__device__ inline bf16x8 cvt8(const float4& a, const float4& b) {
    bf16x8 o;
    o[0] = (bf16)a.x; o[1] = (bf16)a.y; o[2] = (bf16)a.z; o[3] = (bf16)a.w;
    o[4] = (bf16)b.x; o[5] = (bf16)b.y; o[6] = (bf16)b.z; o[7] = (bf16)b.w;
    return o;
}

// ---------------------------------------------------------------------------
// Weight fp32 -> bf16, 9 segments into one contiguous Wall buffer.
// ---------------------------------------------------------------------------
struct ConvArgs {
    const float* src[9];
    bf16*        dst[9];
    int          n[9];
};

__global__ __launch_bounds__(256) void convert_w(ConvArgs args) {
    int seg = blockIdx.y;
    int n   = args.n[seg];
    int i8  = (blockIdx.x * 256 + threadIdx.x) * 8;
    if (i8 >= n) return;
    const float4 a = *(const float4*)(args.src[seg] + i8);
    const float4 b = *(const float4*)(args.src[seg] + i8 + 4);
    *(bf16x8*)(args.dst[seg] + i8) = cvt8(a, b);
}

// ---------------------------------------------------------------------------
__global__ __launch_bounds__(256) void zero_f32(float* __restrict__ p) {
    int i = (blockIdx.x * 256 + threadIdx.x) * 4;
    *(f32x4*)(p + i) = f32x4{0.f, 0.f, 0.f, 0.f};
}

__global__ __launch_bounds__(256) void init_bias(const float* __restrict__ xmid,
                                                 const float* __restrict__ bd,
                                                 float* __restrict__ out) {
    int i4 = (blockIdx.x * 256 + threadIdx.x) * 4;
    int col = i4 % CC;
    float4 a = *(const float4*)(xmid + i4);
    float4 b = *(const float4*)(bd + col);
    *(float4*)(out + i4) = float4{a.x + b.x, a.y + b.y, a.z + b.z, a.w + b.w};
}

// ---------------------------------------------------------------------------
__global__ __launch_bounds__(256) void rope_table(float* __restrict__ cosT, float* __restrict__ sinT) {
    int i = blockIdx.x * 256 + threadIdx.x;   // 65536
    int t = i >> 5, j = i & 31;
    float inv = 1.0f / powf(10000.0f, (float)(2 * j) / 64.0f);
    float f = (float)t * inv;
    cosT[i] = cosf(f);
    sinT[i] = sinf(f);
}

// ---------------------------------------------------------------------------
__global__ __launch_bounds__(256) void rmsnorm(const float* __restrict__ x, bf16* __restrict__ out) {
    int row = blockIdx.x;
    const float* xr = x + (long)row * CC;
    int tid = threadIdx.x;
    float v0 = xr[tid], v1 = xr[tid + 256], v2 = xr[tid + 512];
    float ss = v0 * v0 + v1 * v1 + v2 * v2;
    #pragma unroll
    for (int off = 32; off > 0; off >>= 1) ss += __shfl_down(ss, off);
    __shared__ float red[4];
    if ((tid & 63) == 0) red[tid >> 6] = ss;
    __syncthreads();
    float tot = red[0] + red[1] + red[2] + red[3];
    float sc = rsqrtf(tot * (1.0f / 768.0f) + 1e-6f);
    bf16* o = out + (long)row * CC;
    o[tid]       = (bf16)(v0 * sc);
    o[tid + 256] = (bf16)(v1 * sc);
    o[tid + 512] = (bf16)(v2 * sc);
}

// ---------------------------------------------------------------------------
// GEMM: C[M,N] = A[M,K] @ B[N,K]^T.  A bf16 (fp32 if AF32); B bf16. BK=64.
// 4 waves. BN==128: 2x2; BN==64: 4x1.
// EPI 0: outb=bf16(acc); 1: outf=res+acc; 2: outf=res+bias+acc;
// EPI 3: atomicAdd(outf, acc); EPI 4: bf16 store with fused RoPE (cols<3072).
// ---------------------------------------------------------------------------
template <int EPI, bool AF32, int BM, int BN, int SK>
__global__ __launch_bounds__(256) void gemm_bt(
    const void* __restrict__ Av, const bf16* __restrict__ B,
    bf16* __restrict__ outb, float* __restrict__ outf,
    const float* __restrict__ res, const float* __restrict__ bias,
    const float* __restrict__ cosT, const float* __restrict__ sinT,
    int M, int N, int K)
{
    constexpr int BK = 64, LDR = 72;
    constexpr int WC = BN / 64, WR = 4 / WC, FM = BM / (WR * 16);
    constexpr int RA = BM / 32, RB = BN / 32;
    __shared__ bf16 Al[BM * LDR];
    __shared__ bf16 Bl[BN * LDR];

    const int tid = threadIdx.x, lane = tid & 63, wave = tid >> 6;
    const int wr = wave / WC, wc = wave % WC;
    const int l15 = lane & 15, lhi = lane >> 4;
    const int bm = blockIdx.x * BM, bn = blockIdx.y * BN;

    const int srow = tid >> 3;          // 0..31
    const int scol = (tid & 7) * 8;     // 0..56

    const int kchunk = K / SK;
    const int koff   = (SK > 1) ? blockIdx.z * kchunk : 0;

    const bf16*  Ag  = (const bf16*)Av  + (long)(bm + srow) * K + koff + scol;
    const float* Agf = (const float*)Av + (long)(bm + srow) * K + koff + scol;
    const bf16*  Bg  = B + (long)(bn + srow) * K + koff + scol;

    f32x4 acc[FM][4] = {};
    const int nk = kchunk / BK;

    bf16x8 ga[RA], gb[RB];
    float4 fa[RA][2];
    auto LOAD = [&](int t) {
        #pragma unroll
        for (int i = 0; i < RA; ++i) {
            if constexpr (AF32) {
                const float* p = Agf + (long)i * 32 * K + t * BK;
                fa[i][0] = *(const float4*)(p);
                fa[i][1] = *(const float4*)(p + 4);
            } else {
                ga[i] = *(const bf16x8*)(Ag + (long)i * 32 * K + t * BK);
            }
        }
        #pragma unroll
        for (int i = 0; i < RB; ++i)
            gb[i] = *(const bf16x8*)(Bg + (long)i * 32 * K + t * BK);
    };
    LOAD(0);

    for (int t = 0; t < nk; ++t) {
        __syncthreads();
        #pragma unroll
        for (int i = 0; i < RA; ++i) {
            if constexpr (AF32)
                *(bf16x8*)(&Al[(srow + i * 32) * LDR + scol]) = cvt8(fa[i][0], fa[i][1]);
            else
                *(bf16x8*)(&Al[(srow + i * 32) * LDR + scol]) = ga[i];
        }
        #pragma unroll
        for (int i = 0; i < RB; ++i)
            *(bf16x8*)(&Bl[(srow + i * 32) * LDR + scol]) = gb[i];
        __syncthreads();
        if (t + 1 < nk) LOAD(t + 1);

        bf16x8 afr[FM][2], bfr[4][2];
        #pragma unroll
        for (int m = 0; m < FM; ++m)
            #pragma unroll
            for (int kk = 0; kk < 2; ++kk)
                afr[m][kk] = *(const bf16x8*)(&Al[(wr * FM * 16 + m * 16 + l15) * LDR + kk * 32 + lhi * 8]);
        #pragma unroll
        for (int n = 0; n < 4; ++n)
            #pragma unroll
            for (int kk = 0; kk < 2; ++kk)
                bfr[n][kk] = *(const bf16x8*)(&Bl[(wc * 64 + n * 16 + l15) * LDR + kk * 32 + lhi * 8]);
        #pragma unroll
        for (int kk = 0; kk < 2; ++kk)
            #pragma unroll
            for (int m = 0; m < FM; ++m)
                #pragma unroll
                for (int n = 0; n < 4; ++n)
                    acc[m][n] = MFMA16(afr[m][kk], bfr[n][kk], acc[m][n]);
    }

    if (EPI == 4) {
        // bf16 store with fused RoPE on cols < 3072 (q,k,q2,k2); plain on v.
        const bool dorope = (bn < 3072);
        #pragma unroll
        for (int m = 0; m < FM; ++m) {
            int row0 = bm + wr * FM * 16 + m * 16 + lhi * 4;
            if (dorope) {
                #pragma unroll
                for (int n = 0; n < 2; ++n) {
                    int j   = n * 16 + l15;              // dim-pair index 0..31
                    int col = bn + wc * 64 + n * 16 + l15;
                    #pragma unroll
                    for (int r = 0; r < 4; ++r) {
                        int t = row0 + r;
                        float c = cosT[t * 32 + j], s = sinT[t * 32 + j];
                        float a = acc[m][n][r], b = acc[m][n + 2][r];
                        outb[(long)t * N + col]      = (bf16)(a * c + b * s);
                        outb[(long)t * N + col + 32] = (bf16)(-a * s + b * c);
                    }
                }
            } else {
                #pragma unroll
                for (int n = 0; n < 4; ++n) {
                    int col = bn + wc * 64 + n * 16 + l15;
                    #pragma unroll
                    for (int r = 0; r < 4; ++r)
                        outb[(long)(row0 + r) * N + col] = (bf16)acc[m][n][r];
                }
            }
        }
        return;
    }

    #pragma unroll
    for (int m = 0; m < FM; ++m) {
        #pragma unroll
        for (int n = 0; n < 4; ++n) {
            int row0 = bm + wr * FM * 16 + m * 16 + lhi * 4;
            int col  = bn + wc * 64 + n * 16 + l15;
            #pragma unroll
            for (int r = 0; r < 4; ++r) {
                long idx = (long)(row0 + r) * N + col;
                float v = acc[m][n][r];
                if (EPI == 0) {
                    outb[idx] = (bf16)v;
                } else if (EPI == 1) {
                    outf[idx] = res[idx] + v;
                } else if (EPI == 2) {
                    outf[idx] = res[idx] + bias[col] + v;
                } else {
                    atomicAdd(&outf[idx], v);
                }
            }
        }
    }
}

// ---------------------------------------------------------------------------
// Fused MLP-up: hid = (A@B1^T) * (A@B2^T). 64x128 tile, BK=64, 4 waves 2x2.
// ---------------------------------------------------------------------------
__global__ __launch_bounds__(256) void gemm_mlp_up(
    const bf16* __restrict__ A, const bf16* __restrict__ B1, const bf16* __restrict__ B2,
    bf16* __restrict__ out, int M, int N, int K)
{
    constexpr int BK = 64, LDR = 72;
    __shared__ bf16 Al[64 * LDR];
    __shared__ bf16 B1l[128 * LDR];
    __shared__ bf16 B2l[128 * LDR];

    const int tid = threadIdx.x, lane = tid & 63, wave = tid >> 6;
    const int wr = wave >> 1, wc = wave & 1;
    const int l15 = lane & 15, lhi = lane >> 4;
    const int bm = blockIdx.x * 64, bn = blockIdx.y * 128;

    const int srow = tid >> 3;
    const int scol = (tid & 7) * 8;

    const bf16* Ag  = A  + (long)(bm + srow) * K + scol;
    const bf16* B1g = B1 + (long)(bn + srow) * K + scol;
    const bf16* B2g = B2 + (long)(bn + srow) * K + scol;

    f32x4 acc1[2][4] = {};
    f32x4 acc2[2][4] = {};
    const int nk = K / BK;

    bf16x8 ga[2], g1[4], g2[4];
    auto LOAD = [&](int t) {
        #pragma unroll
        for (int i = 0; i < 2; ++i)
            ga[i] = *(const bf16x8*)(Ag + (long)i * 32 * K + t * BK);
        #pragma unroll
        for (int i = 0; i < 4; ++i) {
            g1[i] = *(const bf16x8*)(B1g + (long)i * 32 * K + t * BK);
            g2[i] = *(const bf16x8*)(B2g + (long)i * 32 * K + t * BK);
        }
    };
    LOAD(0);

    for (int t = 0; t < nk; ++t) {
        __syncthreads();
        #pragma unroll
        for (int i = 0; i < 2; ++i)
            *(bf16x8*)(&Al[(srow + i * 32) * LDR + scol]) = ga[i];
        #pragma unroll
        for (int i = 0; i < 4; ++i) {
            *(bf16x8*)(&B1l[(srow + i * 32) * LDR + scol]) = g1[i];
            *(bf16x8*)(&B2l[(srow + i * 32) * LDR + scol]) = g2[i];
        }
        __syncthreads();
        if (t + 1 < nk) LOAD(t + 1);

        bf16x8 a[2][2], b1[4][2], b2[4][2];
        #pragma unroll
        for (int m = 0; m < 2; ++m)
            #pragma unroll
            for (int kk = 0; kk < 2; ++kk)
                a[m][kk] = *(const bf16x8*)(&Al[(wr * 32 + m * 16 + l15) * LDR + kk * 32 + lhi * 8]);
        #pragma unroll
        for (int n = 0; n < 4; ++n)
            #pragma unroll
            for (int kk = 0; kk < 2; ++kk) {
                b1[n][kk] = *(const bf16x8*)(&B1l[(wc * 64 + n * 16 + l15) * LDR + kk * 32 + lhi * 8]);
                b2[n][kk] = *(const bf16x8*)(&B2l[(wc * 64 + n * 16 + l15) * LDR + kk * 32 + lhi * 8]);
            }
        #pragma unroll
        for (int kk = 0; kk < 2; ++kk)
            #pragma unroll
            for (int m = 0; m < 2; ++m)
                #pragma unroll
                for (int n = 0; n < 4; ++n) {
                    acc1[m][n] = MFMA16(a[m][kk], b1[n][kk], acc1[m][n]);
                    acc2[m][n] = MFMA16(a[m][kk], b2[n][kk], acc2[m][n]);
                }
    }

    #pragma unroll
    for (int m = 0; m < 2; ++m) {
        #pragma unroll
        for (int n = 0; n < 4; ++n) {
            int row0 = bm + wr * 32 + m * 16 + lhi * 4;
            int col  = bn + wc * 64 + n * 16 + l15;
            #pragma unroll
            for (int r = 0; r < 4; ++r)
                out[(long)(row0 + r) * N + col] = (bf16)(acc1[m][n][r] * acc2[m][n][r]);
        }
    }
}

// ---------------------------------------------------------------------------
// Split-K causal quadratic-gated attention. 128-row q-tile, 8 waves (512 thr).
// Per wave: full tiles kt < wkt0, diagonal mask at kt == wkt0, skip above.
// grid (16, 12, 4), qtb = 15-bx (longest-first). fp32 atomicAdd into z.
// ---------------------------------------------------------------------------
__global__ __launch_bounds__(512) void attn(const bf16* __restrict__ qkv, float* __restrict__ z) {
    constexpr int LDK = 72, LDV = 66, LDP = 72;
    __shared__ bf16 Kl[64 * LDK];
    __shared__ bf16 K2l[64 * LDK];
    __shared__ bf16 Vt[64 * LDV];       // Vt[d][k]
    __shared__ bf16 Pl[8][16 * LDP];

    const int qtb = 15 - blockIdx.x, h = blockIdx.y, s = blockIdx.z;
    const int nkt = 2 * qtb + 2;
    const int cb = nkt >> 2, rem = nkt & 3;
    const int len = cb + (s < rem ? 1 : 0);
    if (len == 0) return;
    const int k0 = s * cb + min(s, rem);

    const int tid = threadIdx.x, lane = tid & 63, wave = tid >> 6;
    const int l15 = lane & 15, lhi = lane >> 4;
    const int q0w = qtb * 128 + wave * 16;
    const int wkt0 = q0w >> 6;          // this wave's diagonal k-tile

    const bf16* qbase = qkv + (long)(q0w + l15) * 3840 + h * DHEAD + lhi * 8;
    const bf16x8 qa0  = *(const bf16x8*)(qbase);
    const bf16x8 qa1  = *(const bf16x8*)(qbase + 32);
    const bf16x8 q2a0 = *(const bf16x8*)(qbase + 1536);
    const bf16x8 q2a1 = *(const bf16x8*)(qbase + 1536 + 32);

    f32x4 zacc[4] = {};

    const int srow = tid >> 3;        // 0..63 (512 threads)
    const int scol = (tid & 7) * 8;   // 0..56

    bf16x8 kvr, k2r, vvr;
    auto LOAD = [&](int kt) {
        const bf16* src = qkv + (long)(kt * 64 + srow) * 3840 + h * DHEAD + scol;
        kvr = *(const bf16x8*)(src + 768);
        k2r = *(const bf16x8*)(src + 2304);
        vvr = *(const bf16x8*)(src + 3072);
    };
    LOAD(k0);

    for (int kt = k0; kt < k0 + len; ++kt) {
        __syncthreads();
        *(bf16x8*)(&Kl[srow * LDK + scol])  = kvr;
        *(bf16x8*)(&K2l[srow * LDK + scol]) = k2r;
        #pragma unroll
        for (int e = 0; e < 8; ++e) Vt[(scol + e) * LDV + srow] = vvr[e];
        __syncthreads();
        if (kt + 1 < k0 + len) LOAD(kt + 1);

        if (kt > wkt0) continue;        // fully masked for this wave (barriers already done)
        const bool diag = (kt == wkt0);

        f32x4 s1[4] = {}, s2[4] = {};
        #pragma unroll
        for (int nf = 0; nf < 4; ++nf) {
            bf16x8 kb0 = *(const bf16x8*)(&Kl[(nf * 16 + l15) * LDK + lhi * 8]);
            s1[nf] = MFMA16(qa0, kb0, s1[nf]);
            bf16x8 kb1 = *(const bf16x8*)(&Kl[(nf * 16 + l15) * LDK + 32 + lhi * 8]);
            s1[nf] = MFMA16(qa1, kb1, s1[nf]);
            bf16x8 k2b0 = *(const bf16x8*)(&K2l[(nf * 16 + l15) * LDK + lhi * 8]);
            s2[nf] = MFMA16(q2a0, k2b0, s2[nf]);
            bf16x8 k2b1 = *(const bf16x8*)(&K2l[(nf * 16 + l15) * LDK + 32 + lhi * 8]);
            s2[nf] = MFMA16(q2a1, k2b1, s2[nf]);
        }

        #pragma unroll
        for (int nf = 0; nf < 4; ++nf) {
            #pragma unroll
            for (int r = 0; r < 4; ++r) {
                float p = s1[nf][r] * s2[nf][r] * (1.0f / 4096.0f);
                if (diag) {
                    int qg = q0w + lhi * 4 + r;
                    int kg = kt * 64 + nf * 16 + l15;
                    p = (kg <= qg) ? p : 0.0f;
                }
                Pl[wave][(lhi * 4 + r) * LDP + nf * 16 + l15] = (bf16)p;
            }
        }

        #pragma unroll
        for (int kk = 0; kk < 2; ++kk) {
            bf16x8 pa = *(const bf16x8*)(&Pl[wave][l15 * LDP + kk * 32 + lhi * 8]);
            #pragma unroll
            for (int f = 0; f < 4; ++f) {
                bf16x8 vb = *(const bf16x8*)(&Vt[(f * 16 + l15) * LDV + kk * 32 + lhi * 8]);
                zacc[f] = MFMA16(pa, vb, zacc[f]);
            }
        }
    }

    if (k0 <= wkt0) {                   // wave computed at least one tile
        #pragma unroll
        for (int f = 0; f < 4; ++f) {
            #pragma unroll
            for (int r = 0; r < 4; ++r) {
                atomicAdd(&z[(long)(q0w + lhi * 4 + r) * CC + h * DHEAD + f * 16 + l15], zacc[f][r]);
            }
        }
    }
}

// ---------------------------------------------------------------------------
extern "C" void kernel_launch(void* const* d_in, const int* in_sizes, int n_in,
                              void* d_out, int out_size, void* d_ws, size_t ws_size,
                              hipStream_t stream) {
    const float* x   = (const float*)d_in[0];
    const float* Wq  = (const float*)d_in[1];
    const float* Wk  = (const float*)d_in[2];
    const float* Wq2 = (const float*)d_in[3];
    const float* Wk2 = (const float*)d_in[4];
    const float* Wv  = (const float*)d_in[5];
    const float* Wo  = (const float*)d_in[6];
    const float* Wp1 = (const float*)d_in[7];
    const float* Wp2 = (const float*)d_in[8];
    const float* Wd  = (const float*)d_in[9];
    const float* bd  = (const float*)d_in[10];

    char* ws = (char*)d_ws;
    size_t off = 0;
    auto alloc = [&](size_t bytes) {
        void* p = ws + off;
        off += (bytes + 255) & ~(size_t)255;
        return p;
    };
    // bf16 weights: [Wq|Wk|Wq2|Wk2|Wv | Wo | Wp1 | Wp2 | Wd] = 10,616,832 elems (21.2 MB)
    bf16*  Wall  = (bf16*)alloc(10616832l * 2);
    // activations (41.3 MB); zbuf aliases hid (dead after Wo GEMM). Total 62.5 MB.
    float* xmid  = (float*)alloc(2048l * 768 * 4);
    bf16*  h2    = (bf16*)alloc(2048l * 768 * 2);
    bf16*  hid   = (bf16*)alloc(2048l * 3072 * 2);
    bf16*  h1    = (bf16*)alloc(2048l * 768 * 2);
    float* cosT  = (float*)alloc(2048l * 32 * 4);
    float* sinT  = (float*)alloc(2048l * 32 * 4);
    bf16*  qkv   = (bf16*)alloc(2048l * 3840 * 2);
    float* zbuf  = (float*)hid;   // alias

    const long SW = 589824;       // 768*768
    bf16* Wqkvb = Wall;                    // 5 x SW
    bf16* Wob   = Wall + 5 * SW;
    bf16* Wp1b  = Wall + 6 * SW;           // 2359296
    bf16* Wp2b  = Wp1b + 2359296;
    bf16* Wdb   = Wp2b + 2359296;

    ConvArgs ca;
    const float* wsrc[9] = {Wq, Wk, Wq2, Wk2, Wv, Wo, Wp1, Wp2, Wd};
    bf16* wdst[9] = {Wqkvb, Wqkvb + SW, Wqkvb + 2 * SW, Wqkvb + 3 * SW, Wqkvb + 4 * SW,
                     Wob, Wp1b, Wp2b, Wdb};
    int wn[9] = {589824, 589824, 589824, 589824, 589824, 589824, 2359296, 2359296, 2359296};
    for (int i = 0; i < 9; ++i) { ca.src[i] = wsrc[i]; ca.dst[i] = wdst[i]; ca.n[i] = wn[i]; }

    convert_w<<<dim3(1152, 9), 256, 0, stream>>>(ca);
    rope_table<<<dim3(256), 256, 0, stream>>>(cosT, sinT);
    rmsnorm<<<dim3(2048), 256, 0, stream>>>(x, h1);
    // qkv: 128x128 tiles, fused RoPE epilogue (EPI 4) -> 480 blocks
    gemm_bt<4, false, 128, 128, 1><<<dim3(16, 30), 256, 0, stream>>>(
        h1, Wqkvb, qkv, nullptr, nullptr, nullptr, cosT, sinT, 2048, 3840, 768);
    zero_f32<<<dim3(1536), 256, 0, stream>>>(zbuf);
    // attn: 128-row q-tiles, 8 waves, SK=4, longest-first
    attn<<<dim3(16, 12, 4), 512, 0, stream>>>(qkv, zbuf);
    // xmid = x, then Wo split-K atomic accumulate: 64x64 BK=64, SK=2
    hipMemcpyAsync(xmid, x, 2048l * 768 * 4, hipMemcpyDeviceToDevice, stream);
    gemm_bt<3, true, 64, 64, 2><<<dim3(32, 12, 2), 256, 0, stream>>>(
        zbuf, Wob, nullptr, xmid, nullptr, nullptr, nullptr, nullptr, 2048, 768, 768);
    rmsnorm<<<dim3(2048), 256, 0, stream>>>(xmid, h2);
    // MLP up: 64x128 tiles -> 768 blocks
    gemm_mlp_up<<<dim3(32, 24), 256, 0, stream>>>(h2, Wp1b, Wp2b, hid, 2048, 3072, 768);
    // d_out = xmid + bd, then Wd split-K atomic accumulate: 64x64 BK=64, SK=2
    init_bias<<<dim3(1536), 256, 0, stream>>>(xmid, bd, (float*)d_out);
    gemm_bt<3, false, 64, 64, 2><<<dim3(32, 12, 2), 256, 0, stream>>>(
        hid, Wdb, nullptr, (float*)d_out, nullptr, nullptr, nullptr, nullptr, 2048, 768, 3072);
}

// Round 11
// 239.834 us; speedup vs baseline: 1.6116x; 1.0431x over previous
//
#include <hip/hip_runtime.h>
#include <hip/hip_bf16.h>

typedef __bf16 bf16;
typedef bf16 bf16x8 __attribute__((ext_vector_type(8)));
typedef float f32x4 __attribute__((ext_vector_type(4)));

#define MFMA16(a, b, c) __builtin_amdgcn_mfma_f32_16x16x32_bf16((a), (b), (c), 0, 0, 0)

static constexpr int TT    = 2048;
static constexpr int CC    = 768;
static constexpr int NHEAD = 12;
static constexpr int DHEAD = 64;

__device__ inline bf16x8 cvt8(const float4& a, const float4& b) {
    bf16x8 o;
    o[0] = (bf16)a.x; o[1] = (bf16)a.y; o[2] = (bf16)a.z; o[3] = (bf16)a.w;
    o[4] = (bf16)b.x; o[5] = (bf16)b.y; o[6] = (bf16)b.z; o[7] = (bf16)b.w;
    return o;
}

// ---------------------------------------------------------------------------
// Weight fp32 -> bf16 (9 segments) + zbuf zero-fill (segment 9, src=null).
// ---------------------------------------------------------------------------
struct ConvArgs {
    const float* src[10];
    bf16*        dst[10];
    int          n[10];
};

__global__ __launch_bounds__(256) void convert_w(ConvArgs args) {
    int seg = blockIdx.y;
    int n   = args.n[seg];
    int i8  = (blockIdx.x * 256 + threadIdx.x) * 8;
    if (i8 >= n) return;
    if (args.src[seg] == nullptr) {
        *(bf16x8*)(args.dst[seg] + i8) = bf16x8{};   // fp32 0.0 bit pattern
        return;
    }
    const float4 a = *(const float4*)(args.src[seg] + i8);
    const float4 b = *(const float4*)(args.src[seg] + i8 + 4);
    *(bf16x8*)(args.dst[seg] + i8) = cvt8(a, b);
}

// ---------------------------------------------------------------------------
__global__ __launch_bounds__(256) void init_bias(const float* __restrict__ xmid,
                                                 const float* __restrict__ bd,
                                                 float* __restrict__ out) {
    int i4 = (blockIdx.x * 256 + threadIdx.x) * 4;
    int col = i4 % CC;
    float4 a = *(const float4*)(xmid + i4);
    float4 b = *(const float4*)(bd + col);
    *(float4*)(out + i4) = float4{a.x + b.x, a.y + b.y, a.z + b.z, a.w + b.w};
}

// ---------------------------------------------------------------------------
__global__ __launch_bounds__(256) void rope_table(float* __restrict__ cosT, float* __restrict__ sinT) {
    int i = blockIdx.x * 256 + threadIdx.x;   // 65536
    int t = i >> 5, j = i & 31;
    float inv = 1.0f / powf(10000.0f, (float)(2 * j) / 64.0f);
    float f = (float)t * inv;
    cosT[i] = cosf(f);
    sinT[i] = sinf(f);
}

// ---------------------------------------------------------------------------
__global__ __launch_bounds__(256) void rmsnorm(const float* __restrict__ x, bf16* __restrict__ out) {
    int row = blockIdx.x;
    const float* xr = x + (long)row * CC;
    int tid = threadIdx.x;
    float v0 = xr[tid], v1 = xr[tid + 256], v2 = xr[tid + 512];
    float ss = v0 * v0 + v1 * v1 + v2 * v2;
    #pragma unroll
    for (int off = 32; off > 0; off >>= 1) ss += __shfl_down(ss, off);
    __shared__ float red[4];
    if ((tid & 63) == 0) red[tid >> 6] = ss;
    __syncthreads();
    float tot = red[0] + red[1] + red[2] + red[3];
    float sc = rsqrtf(tot * (1.0f / 768.0f) + 1e-6f);
    bf16* o = out + (long)row * CC;
    o[tid]       = (bf16)(v0 * sc);
    o[tid + 256] = (bf16)(v1 * sc);
    o[tid + 512] = (bf16)(v2 * sc);
}

// ---------------------------------------------------------------------------
// GEMM: C[M,N] = A[M,K] @ B[N,K]^T.  A bf16 (fp32 if AF32); B bf16. BK=64.
// 4 waves. BN==128: 2x2; BN==64: 4x1.
// EPI 0: outb=bf16(acc); 1: outf=res+acc; 2: outf=res+bias+acc;
// EPI 3: atomicAdd(outf, acc); EPI 4: bf16 store with fused RoPE (cols<3072).
// ---------------------------------------------------------------------------
template <int EPI, bool AF32, int BM, int BN, int SK>
__global__ __launch_bounds__(256) void gemm_bt(
    const void* __restrict__ Av, const bf16* __restrict__ B,
    bf16* __restrict__ outb, float* __restrict__ outf,
    const float* __restrict__ res, const float* __restrict__ bias,
    const float* __restrict__ cosT, const float* __restrict__ sinT,
    int M, int N, int K)
{
    constexpr int BK = 64, LDR = 72;
    constexpr int WC = BN / 64, WR = 4 / WC, FM = BM / (WR * 16);
    constexpr int RA = BM / 32, RB = BN / 32;
    __shared__ bf16 Al[BM * LDR];
    __shared__ bf16 Bl[BN * LDR];

    const int tid = threadIdx.x, lane = tid & 63, wave = tid >> 6;
    const int wr = wave / WC, wc = wave % WC;
    const int l15 = lane & 15, lhi = lane >> 4;
    const int bm = blockIdx.x * BM, bn = blockIdx.y * BN;

    const int srow = tid >> 3;          // 0..31
    const int scol = (tid & 7) * 8;     // 0..56

    const int kchunk = K / SK;
    const int koff   = (SK > 1) ? blockIdx.z * kchunk : 0;

    const bf16*  Ag  = (const bf16*)Av  + (long)(bm + srow) * K + koff + scol;
    const float* Agf = (const float*)Av + (long)(bm + srow) * K + koff + scol;
    const bf16*  Bg  = B + (long)(bn + srow) * K + koff + scol;

    f32x4 acc[FM][4] = {};
    const int nk = kchunk / BK;

    bf16x8 ga[RA], gb[RB];
    float4 fa[RA][2];
    auto LOAD = [&](int t) {
        #pragma unroll
        for (int i = 0; i < RA; ++i) {
            if constexpr (AF32) {
                const float* p = Agf + (long)i * 32 * K + t * BK;
                fa[i][0] = *(const float4*)(p);
                fa[i][1] = *(const float4*)(p + 4);
            } else {
                ga[i] = *(const bf16x8*)(Ag + (long)i * 32 * K + t * BK);
            }
        }
        #pragma unroll
        for (int i = 0; i < RB; ++i)
            gb[i] = *(const bf16x8*)(Bg + (long)i * 32 * K + t * BK);
    };
    LOAD(0);

    for (int t = 0; t < nk; ++t) {
        __syncthreads();
        #pragma unroll
        for (int i = 0; i < RA; ++i) {
            if constexpr (AF32)
                *(bf16x8*)(&Al[(srow + i * 32) * LDR + scol]) = cvt8(fa[i][0], fa[i][1]);
            else
                *(bf16x8*)(&Al[(srow + i * 32) * LDR + scol]) = ga[i];
        }
        #pragma unroll
        for (int i = 0; i < RB; ++i)
            *(bf16x8*)(&Bl[(srow + i * 32) * LDR + scol]) = gb[i];
        __syncthreads();
        if (t + 1 < nk) LOAD(t + 1);

        bf16x8 afr[FM][2], bfr[4][2];
        #pragma unroll
        for (int m = 0; m < FM; ++m)
            #pragma unroll
            for (int kk = 0; kk < 2; ++kk)
                afr[m][kk] = *(const bf16x8*)(&Al[(wr * FM * 16 + m * 16 + l15) * LDR + kk * 32 + lhi * 8]);
        #pragma unroll
        for (int n = 0; n < 4; ++n)
            #pragma unroll
            for (int kk = 0; kk < 2; ++kk)
                bfr[n][kk] = *(const bf16x8*)(&Bl[(wc * 64 + n * 16 + l15) * LDR + kk * 32 + lhi * 8]);
        #pragma unroll
        for (int kk = 0; kk < 2; ++kk)
            #pragma unroll
            for (int m = 0; m < FM; ++m)
                #pragma unroll
                for (int n = 0; n < 4; ++n)
                    acc[m][n] = MFMA16(afr[m][kk], bfr[n][kk], acc[m][n]);
    }

    if (EPI == 4) {
        const bool dorope = (bn < 3072);
        #pragma unroll
        for (int m = 0; m < FM; ++m) {
            int row0 = bm + wr * FM * 16 + m * 16 + lhi * 4;
            if (dorope) {
                #pragma unroll
                for (int n = 0; n < 2; ++n) {
                    int j   = n * 16 + l15;
                    int col = bn + wc * 64 + n * 16 + l15;
                    #pragma unroll
                    for (int r = 0; r < 4; ++r) {
                        int t = row0 + r;
                        float c = cosT[t * 32 + j], s = sinT[t * 32 + j];
                        float a = acc[m][n][r], b = acc[m][n + 2][r];
                        outb[(long)t * N + col]      = (bf16)(a * c + b * s);
                        outb[(long)t * N + col + 32] = (bf16)(-a * s + b * c);
                    }
                }
            } else {
                #pragma unroll
                for (int n = 0; n < 4; ++n) {
                    int col = bn + wc * 64 + n * 16 + l15;
                    #pragma unroll
                    for (int r = 0; r < 4; ++r)
                        outb[(long)(row0 + r) * N + col] = (bf16)acc[m][n][r];
                }
            }
        }
        return;
    }

    #pragma unroll
    for (int m = 0; m < FM; ++m) {
        #pragma unroll
        for (int n = 0; n < 4; ++n) {
            int row0 = bm + wr * FM * 16 + m * 16 + lhi * 4;
            int col  = bn + wc * 64 + n * 16 + l15;
            #pragma unroll
            for (int r = 0; r < 4; ++r) {
                long idx = (long)(row0 + r) * N + col;
                float v = acc[m][n][r];
                if (EPI == 0) {
                    outb[idx] = (bf16)v;
                } else if (EPI == 1) {
                    outf[idx] = res[idx] + v;
                } else if (EPI == 2) {
                    outf[idx] = res[idx] + bias[col] + v;
                } else {
                    atomicAdd(&outf[idx], v);
                }
            }
        }
    }
}

// ---------------------------------------------------------------------------
// Fused MLP-up: hid = (A@B1^T) * (A@B2^T). 64x128 tile, BK=64, 4 waves 2x2.
// ---------------------------------------------------------------------------
__global__ __launch_bounds__(256) void gemm_mlp_up(
    const bf16* __restrict__ A, const bf16* __restrict__ B1, const bf16* __restrict__ B2,
    bf16* __restrict__ out, int M, int N, int K)
{
    constexpr int BK = 64, LDR = 72;
    __shared__ bf16 Al[64 * LDR];
    __shared__ bf16 B1l[128 * LDR];
    __shared__ bf16 B2l[128 * LDR];

    const int tid = threadIdx.x, lane = tid & 63, wave = tid >> 6;
    const int wr = wave >> 1, wc = wave & 1;
    const int l15 = lane & 15, lhi = lane >> 4;
    const int bm = blockIdx.x * 64, bn = blockIdx.y * 128;

    const int srow = tid >> 3;
    const int scol = (tid & 7) * 8;

    const bf16* Ag  = A  + (long)(bm + srow) * K + scol;
    const bf16* B1g = B1 + (long)(bn + srow) * K + scol;
    const bf16* B2g = B2 + (long)(bn + srow) * K + scol;

    f32x4 acc1[2][4] = {};
    f32x4 acc2[2][4] = {};
    const int nk = K / BK;

    bf16x8 ga[2], g1[4], g2[4];
    auto LOAD = [&](int t) {
        #pragma unroll
        for (int i = 0; i < 2; ++i)
            ga[i] = *(const bf16x8*)(Ag + (long)i * 32 * K + t * BK);
        #pragma unroll
        for (int i = 0; i < 4; ++i) {
            g1[i] = *(const bf16x8*)(B1g + (long)i * 32 * K + t * BK);
            g2[i] = *(const bf16x8*)(B2g + (long)i * 32 * K + t * BK);
        }
    };
    LOAD(0);

    for (int t = 0; t < nk; ++t) {
        __syncthreads();
        #pragma unroll
        for (int i = 0; i < 2; ++i)
            *(bf16x8*)(&Al[(srow + i * 32) * LDR + scol]) = ga[i];
        #pragma unroll
        for (int i = 0; i < 4; ++i) {
            *(bf16x8*)(&B1l[(srow + i * 32) * LDR + scol]) = g1[i];
            *(bf16x8*)(&B2l[(srow + i * 32) * LDR + scol]) = g2[i];
        }
        __syncthreads();
        if (t + 1 < nk) LOAD(t + 1);

        bf16x8 a[2][2], b1[4][2], b2[4][2];
        #pragma unroll
        for (int m = 0; m < 2; ++m)
            #pragma unroll
            for (int kk = 0; kk < 2; ++kk)
                a[m][kk] = *(const bf16x8*)(&Al[(wr * 32 + m * 16 + l15) * LDR + kk * 32 + lhi * 8]);
        #pragma unroll
        for (int n = 0; n < 4; ++n)
            #pragma unroll
            for (int kk = 0; kk < 2; ++kk) {
                b1[n][kk] = *(const bf16x8*)(&B1l[(wc * 64 + n * 16 + l15) * LDR + kk * 32 + lhi * 8]);
                b2[n][kk] = *(const bf16x8*)(&B2l[(wc * 64 + n * 16 + l15) * LDR + kk * 32 + lhi * 8]);
            }
        #pragma unroll
        for (int kk = 0; kk < 2; ++kk)
            #pragma unroll
            for (int m = 0; m < 2; ++m)
                #pragma unroll
                for (int n = 0; n < 4; ++n) {
                    acc1[m][n] = MFMA16(a[m][kk], b1[n][kk], acc1[m][n]);
                    acc2[m][n] = MFMA16(a[m][kk], b2[n][kk], acc2[m][n]);
                }
    }

    #pragma unroll
    for (int m = 0; m < 2; ++m) {
        #pragma unroll
        for (int n = 0; n < 4; ++n) {
            int row0 = bm + wr * 32 + m * 16 + lhi * 4;
            int col  = bn + wc * 64 + n * 16 + l15;
            #pragma unroll
            for (int r = 0; r < 4; ++r)
                out[(long)(row0 + r) * N + col] = (bf16)(acc1[m][n][r] * acc2[m][n][r]);
        }
    }
}

// ---------------------------------------------------------------------------
// Split-K causal quadratic-gated attention. 128-row q-tile, 8 waves (512 thr).
// Double-buffered K/K2/Vt LDS: ONE barrier per k-tile.
// grid (16, 12, 4), qtb = 15-bx (longest-first). fp32 atomicAdd into z.
// ---------------------------------------------------------------------------
__global__ __launch_bounds__(512) void attn(const bf16* __restrict__ qkv, float* __restrict__ z) {
    constexpr int LDK = 72, LDV = 66, LDP = 72;
    __shared__ bf16 Kl[2][64 * LDK];
    __shared__ bf16 K2l[2][64 * LDK];
    __shared__ bf16 Vt[2][64 * LDV];    // Vt[d][k]
    __shared__ bf16 Pl[8][16 * LDP];

    const int qtb = 15 - blockIdx.x, h = blockIdx.y, s = blockIdx.z;
    const int nkt = 2 * qtb + 2;
    const int cb = nkt >> 2, rem = nkt & 3;
    const int len = cb + (s < rem ? 1 : 0);
    if (len == 0) return;
    const int k0 = s * cb + min(s, rem);

    const int tid = threadIdx.x, lane = tid & 63, wave = tid >> 6;
    const int l15 = lane & 15, lhi = lane >> 4;
    const int q0w = qtb * 128 + wave * 16;
    const int wkt0 = q0w >> 6;          // this wave's diagonal k-tile

    const bf16* qbase = qkv + (long)(q0w + l15) * 3840 + h * DHEAD + lhi * 8;
    const bf16x8 qa0  = *(const bf16x8*)(qbase);
    const bf16x8 qa1  = *(const bf16x8*)(qbase + 32);
    const bf16x8 q2a0 = *(const bf16x8*)(qbase + 1536);
    const bf16x8 q2a1 = *(const bf16x8*)(qbase + 1536 + 32);

    f32x4 zacc[4] = {};

    const int srow = tid >> 3;        // 0..63 (512 threads)
    const int scol = (tid & 7) * 8;   // 0..56

    bf16x8 kvr, k2r, vvr;
    auto LOAD = [&](int kt) {
        const bf16* src = qkv + (long)(kt * 64 + srow) * 3840 + h * DHEAD + scol;
        kvr = *(const bf16x8*)(src + 768);
        k2r = *(const bf16x8*)(src + 2304);
        vvr = *(const bf16x8*)(src + 3072);
    };
    LOAD(k0);

    int cur = 0;
    for (int kt = k0; kt < k0 + len; ++kt, cur ^= 1) {
        // stage buffer `cur` (regs -> LDS), single barrier, then compute.
        *(bf16x8*)(&Kl[cur][srow * LDK + scol])  = kvr;
        *(bf16x8*)(&K2l[cur][srow * LDK + scol]) = k2r;
        #pragma unroll
        for (int e = 0; e < 8; ++e) Vt[cur][(scol + e) * LDV + srow] = vvr[e];
        __syncthreads();
        if (kt + 1 < k0 + len) LOAD(kt + 1);

        if (kt > wkt0) continue;        // masked-out tile for this wave
        const bool diag = (kt == wkt0);

        f32x4 s1[4] = {}, s2[4] = {};
        #pragma unroll
        for (int nf = 0; nf < 4; ++nf) {
            bf16x8 kb0 = *(const bf16x8*)(&Kl[cur][(nf * 16 + l15) * LDK + lhi * 8]);
            s1[nf] = MFMA16(qa0, kb0, s1[nf]);
            bf16x8 kb1 = *(const bf16x8*)(&Kl[cur][(nf * 16 + l15) * LDK + 32 + lhi * 8]);
            s1[nf] = MFMA16(qa1, kb1, s1[nf]);
            bf16x8 k2b0 = *(const bf16x8*)(&K2l[cur][(nf * 16 + l15) * LDK + lhi * 8]);
            s2[nf] = MFMA16(q2a0, k2b0, s2[nf]);
            bf16x8 k2b1 = *(const bf16x8*)(&K2l[cur][(nf * 16 + l15) * LDK + 32 + lhi * 8]);
            s2[nf] = MFMA16(q2a1, k2b1, s2[nf]);
        }

        #pragma unroll
        for (int nf = 0; nf < 4; ++nf) {
            #pragma unroll
            for (int r = 0; r < 4; ++r) {
                float p = s1[nf][r] * s2[nf][r] * (1.0f / 4096.0f);
                if (diag) {
                    int qg = q0w + lhi * 4 + r;
                    int kg = kt * 64 + nf * 16 + l15;
                    p = (kg <= qg) ? p : 0.0f;
                }
                Pl[wave][(lhi * 4 + r) * LDP + nf * 16 + l15] = (bf16)p;
            }
        }

        #pragma unroll
        for (int kk = 0; kk < 2; ++kk) {
            bf16x8 pa = *(const bf16x8*)(&Pl[wave][l15 * LDP + kk * 32 + lhi * 8]);
            #pragma unroll
            for (int f = 0; f < 4; ++f) {
                bf16x8 vb = *(const bf16x8*)(&Vt[cur][(f * 16 + l15) * LDV + kk * 32 + lhi * 8]);
                zacc[f] = MFMA16(pa, vb, zacc[f]);
            }
        }
    }

    if (k0 <= wkt0) {
        #pragma unroll
        for (int f = 0; f < 4; ++f) {
            #pragma unroll
            for (int r = 0; r < 4; ++r) {
                atomicAdd(&z[(long)(q0w + lhi * 4 + r) * CC + h * DHEAD + f * 16 + l15], zacc[f][r]);
            }
        }
    }
}

// ---------------------------------------------------------------------------
extern "C" void kernel_launch(void* const* d_in, const int* in_sizes, int n_in,
                              void* d_out, int out_size, void* d_ws, size_t ws_size,
                              hipStream_t stream) {
    const float* x   = (const float*)d_in[0];
    const float* Wq  = (const float*)d_in[1];
    const float* Wk  = (const float*)d_in[2];
    const float* Wq2 = (const float*)d_in[3];
    const float* Wk2 = (const float*)d_in[4];
    const float* Wv  = (const float*)d_in[5];
    const float* Wo  = (const float*)d_in[6];
    const float* Wp1 = (const float*)d_in[7];
    const float* Wp2 = (const float*)d_in[8];
    const float* Wd  = (const float*)d_in[9];
    const float* bd  = (const float*)d_in[10];

    char* ws = (char*)d_ws;
    size_t off = 0;
    auto alloc = [&](size_t bytes) {
        void* p = ws + off;
        off += (bytes + 255) & ~(size_t)255;
        return p;
    };
    // bf16 weights (21.2 MB) + activations; zbuf aliases hid. Total ~62.5 MB.
    bf16*  Wall  = (bf16*)alloc(10616832l * 2);
    float* xmid  = (float*)alloc(2048l * 768 * 4);
    bf16*  h2    = (bf16*)alloc(2048l * 768 * 2);
    bf16*  hid   = (bf16*)alloc(2048l * 3072 * 2);
    bf16*  h1    = (bf16*)alloc(2048l * 768 * 2);
    float* cosT  = (float*)alloc(2048l * 32 * 4);
    float* sinT  = (float*)alloc(2048l * 32 * 4);
    bf16*  qkv   = (bf16*)alloc(2048l * 3840 * 2);
    float* zbuf  = (float*)hid;   // alias

    const long SW = 589824;       // 768*768
    bf16* Wqkvb = Wall;
    bf16* Wob   = Wall + 5 * SW;
    bf16* Wp1b  = Wall + 6 * SW;
    bf16* Wp2b  = Wp1b + 2359296;
    bf16* Wdb   = Wp2b + 2359296;

    ConvArgs ca;
    const float* wsrc[10] = {Wq, Wk, Wq2, Wk2, Wv, Wo, Wp1, Wp2, Wd, nullptr};
    bf16* wdst[10] = {Wqkvb, Wqkvb + SW, Wqkvb + 2 * SW, Wqkvb + 3 * SW, Wqkvb + 4 * SW,
                      Wob, Wp1b, Wp2b, Wdb, (bf16*)zbuf};
    int wn[10] = {589824, 589824, 589824, 589824, 589824, 589824,
                  2359296, 2359296, 2359296, 3145728};   // last = zbuf as bf16 elems
    for (int i = 0; i < 10; ++i) { ca.src[i] = wsrc[i]; ca.dst[i] = wdst[i]; ca.n[i] = wn[i]; }

    convert_w<<<dim3(1536, 10), 256, 0, stream>>>(ca);
    rope_table<<<dim3(256), 256, 0, stream>>>(cosT, sinT);
    rmsnorm<<<dim3(2048), 256, 0, stream>>>(x, h1);
    // qkv: 128x128 tiles, fused RoPE epilogue (EPI 4) -> 480 blocks
    gemm_bt<4, false, 128, 128, 1><<<dim3(16, 30), 256, 0, stream>>>(
        h1, Wqkvb, qkv, nullptr, nullptr, nullptr, cosT, sinT, 2048, 3840, 768);
    // attn: 128-row q-tiles, 8 waves, dbuf single-barrier, SK=4, longest-first
    attn<<<dim3(16, 12, 4), 512, 0, stream>>>(qkv, zbuf);
    // Wo: direct res-add epilogue (xmid = x + z@Wo^T), SK=1 -> 384 blocks
    gemm_bt<1, true, 64, 64, 1><<<dim3(32, 12), 256, 0, stream>>>(
        zbuf, Wob, nullptr, xmid, x, nullptr, nullptr, nullptr, 2048, 768, 768);
    rmsnorm<<<dim3(2048), 256, 0, stream>>>(xmid, h2);
    // MLP up: 64x128 tiles -> 768 blocks
    gemm_mlp_up<<<dim3(32, 24), 256, 0, stream>>>(h2, Wp1b, Wp2b, hid, 2048, 3072, 768);
    // d_out = xmid + bd, then Wd split-K atomic accumulate: 64x64 BK=64, SK=2
    init_bias<<<dim3(1536), 256, 0, stream>>>(xmid, bd, (float*)d_out);
    gemm_bt<3, false, 64, 64, 2><<<dim3(32, 12, 2), 256, 0, stream>>>(
        hid, Wdb, nullptr, (float*)d_out, nullptr, nullptr, nullptr, nullptr, 2048, 768, 3072);
}